// Round 15
// baseline (182.717 us; speedup 1.0000x reference)
//
#include <hip/hip_runtime.h>
#include <hip/hip_bf16.h>
#include <cstdint>
#include <cstddef>

// ---------- types ----------
using u16 = unsigned short;
typedef __attribute__((ext_vector_type(4))) float f32x4;
typedef __attribute__((ext_vector_type(16))) float f32x16;
typedef __attribute__((ext_vector_type(8))) unsigned short u16x8;
typedef __attribute__((ext_vector_type(4))) unsigned short u16x4;
typedef __attribute__((ext_vector_type(4))) unsigned int u32x4;
typedef __bf16 bfrag __attribute__((ext_vector_type(8)));   // 8 bf16 = 4 VGPR MFMA operand

constexpr int Hn = 8, Cn = 1024, Dn = 128, Fn = 512, Bn = 16;
constexpr int M1 = Bn * Cn;  // 16384 rows of x / att_out

// workspace layout (bytes)
constexpr size_t OFF_XB  = 0;                                  // x bf16 [16384][512]
constexpr size_t SZ_XB   = (size_t)M1 * Fn * 2;                // 16 MiB
constexpr size_t OFF_WT  = OFF_XB + SZ_XB;                     // Wt bf16 [3][1024][512] (q,k,v)
constexpr size_t SZ_WT   = 3ull * 1024 * 512 * 2;              // 3 MiB
constexpr size_t OFF_W0T = OFF_WT + SZ_WT;                     // Ww0^T bf16 [128][1024]
constexpr size_t SZ_W0T  = 128ull * 1024 * 2;
constexpr size_t OFF_Q   = OFF_W0T + SZ_W0T;                   // q perm [16][8][1024][128] bf16
constexpr size_t SZ_P    = (size_t)Bn * Hn * Cn * Dn * 2;      // 32 MiB each
constexpr size_t OFF_K   = OFF_Q + SZ_P;
constexpr size_t OFF_V   = OFF_K + SZ_P;                       // V^T: [bh][128 d][1024 c]
constexpr size_t OFF_ATT = OFF_V + SZ_P;                       // vals2 bf16 [16384][1024]
// NOTE buffer reuse: qkv writes perm-V into OFF_ATT (dead until attn output);
// vtrans transposes OFF_ATT -> OFF_V; attn then overwrites OFF_ATT.

// ---------- helpers ----------
__device__ __forceinline__ float bf2f(u16 u) {
  unsigned int x = ((unsigned int)u) << 16;
  return __builtin_bit_cast(float, x);
}
__device__ __forceinline__ u16 f2bf(float f) {
  unsigned int u = __builtin_bit_cast(unsigned int, f);
  u += 0x7fffu + ((u >> 16) & 1u);   // RNE
  return (u16)(u >> 16);
}
__device__ __forceinline__ f32x4 mfma16(bfrag a, bfrag b, f32x4 c) {
  return __builtin_amdgcn_mfma_f32_16x16x32_bf16(a, b, c, 0, 0, 0);
}
__device__ __forceinline__ f32x16 mfma32(bfrag a, bfrag b, f32x16 c) {
  return __builtin_amdgcn_mfma_f32_32x32x16_bf16(a, b, c, 0, 0, 0);
}
// async 16B global->LDS; lds base must be wave-uniform (lane*16 auto-offset)
__device__ __forceinline__ void gload16(const void* g, void* lds) {
  __builtin_amdgcn_global_load_lds(
      (const __attribute__((address_space(1))) unsigned int*)g,
      (__attribute__((address_space(3))) unsigned int*)lds, 16, 0, 0);
}
__device__ __forceinline__ unsigned cvtpk(float lo, float hi) {
  unsigned r;
  asm("v_cvt_pk_bf16_f32 %0, %1, %2" : "=v"(r) : "v"(lo), "v"(hi));
  return r;
}
// raw HW exp2 (1 instr; valid here: |x| < ~2 by construction)
__device__ __forceinline__ float fexp2(float x) {
  float r;
  asm("v_exp_f32 %0, %1" : "=v"(r) : "v"(x));
  return r;
}

// ---------- prep kernels ----------
__global__ void cvt_bf16(const float* __restrict__ in, u16* __restrict__ out, int n) {
  int idx = (blockIdx.x * blockDim.x + threadIdx.x) * 4;
  if (idx < n) {
    float4 v = *(const float4*)(in + idx);
    u16x4 o;
    o.x = f2bf(v.x); o.y = f2bf(v.y); o.z = f2bf(v.z); o.w = f2bf(v.w);
    *(u16x4*)(out + idx) = o;
  }
}

// in [R][Cc] f32 -> out [Cc][R] bf16 ; block (32,8), grid (Cc/32, R/32)
__global__ void transpose_cvt(const float* __restrict__ in, u16* __restrict__ out,
                              int R, int Cc) {
  __shared__ float tile[32][33];
  int c0 = blockIdx.x * 32, r0 = blockIdx.y * 32;
  int tx = threadIdx.x, ty = threadIdx.y;
#pragma unroll
  for (int i = 0; i < 4; ++i)
    tile[ty + i * 8][tx] = in[(size_t)(r0 + ty + i * 8) * Cc + c0 + tx];
  __syncthreads();
#pragma unroll
  for (int i = 0; i < 4; ++i)
    out[(size_t)(c0 + ty + i * 8) * R + r0 + tx] = f2bf(tile[tx][ty + i * 8]);
}

// fused: the three 512x1024 weight transposes in one launch (z = which matrix)
__global__ void transpose_cvt3(const float* __restrict__ W0, const float* __restrict__ W1,
                               const float* __restrict__ W2, u16* __restrict__ out) {
  __shared__ float tile[32][33];
  const int z = blockIdx.z;
  const float* in = (z == 0) ? W0 : (z == 1) ? W1 : W2;
  u16* op = out + (size_t)z * 1024 * 512;
  int c0 = blockIdx.x * 32, r0 = blockIdx.y * 32;
  int tx = threadIdx.x, ty = threadIdx.y;
#pragma unroll
  for (int i = 0; i < 4; ++i)
    tile[ty + i * 8][tx] = in[(size_t)(r0 + ty + i * 8) * 1024 + c0 + tx];
  __syncthreads();
#pragma unroll
  for (int i = 0; i < 4; ++i)
    op[(size_t)(c0 + ty + i * 8) * 512 + r0 + tx] = f2bf(tile[tx][ty + i * 8]);
}

// per-head V transpose: in [bh][1024 c'][128 d] u16 -> out [bh][128 d][1024 c']
// block (32,8), grid (4 d-tiles, 32 c-tiles, 128 bh)
__global__ void vtrans(const u16* __restrict__ in, u16* __restrict__ out) {
  __shared__ u16 tile[32][33];
  int d0 = blockIdx.x * 32, c0 = blockIdx.y * 32, bh = blockIdx.z;
  const u16* ip = in + (size_t)bh * (Cn * Dn);
  u16* op = out + (size_t)bh * (Dn * Cn);
  int tx = threadIdx.x, ty = threadIdx.y;
#pragma unroll
  for (int i = 0; i < 4; ++i)
    tile[ty + i * 8][tx] = ip[(size_t)(c0 + ty + i * 8) * Dn + d0 + tx];
  __syncthreads();
#pragma unroll
  for (int i = 0; i < 4; ++i)
    op[(size_t)(d0 + ty + i * 8) * Cn + c0 + tx] = tile[tx][ty + i * 8];
}

// ---------- QKV projection GEMM (256x256 tile, 8 waves, phased 1-barrier loop) ----------
// Q output pre-scaled by log2(e)/sqrt(D); outputs in perm layout [bh][c'][d];
// V transposed afterwards by vtrans.  BM=BN=256, BK=64, 512 threads (8 waves,
// 2m x 4n), wave tile 128x64 (acc 128 VGPR).  LDS: 2 buffers x (A 32KB + B
// 32KB) = 128KB -> 1 block/CU.  Per K-tile: 4 phases, each {issue 2 of next
// tile's 8 loads into buf[cur^1] | 8 ds_read_b128 | 16 MFMA w/ setprio};
// ONE __syncthreads() per K-tile.  Race-free: buf[cur] never written while
// read (next tile targets the other buffer, whose readers passed the previous
// barrier); boundary's vmcnt(0) waits only on loads given >=4 phases to land.
// vs R12's 128^2 2-barrier: 2x FLOP per staged byte, half the barriers.
__global__ __launch_bounds__(512, 1)
void qkv_gemm(const u16* __restrict__ xb, const u16* __restrict__ wt,
              const float* __restrict__ bq, const float* __restrict__ bk,
              const float* __restrict__ bv,
              u16* __restrict__ qout, u16* __restrict__ kout,
              u16* __restrict__ vout) {
  __shared__ u16 smem[2 * 32768];   // buf b at b*65536 B: A[256][64] | B[256][64]
  char* smb = (char*)smem;

  // XCD-chunked 1D grid: 768 = 8 x 96 (bijective)
  const int bid = blockIdx.x;
  const int wg = (bid & 7) * 96 + (bid >> 3);
  const int mt = wg / 12, rem = wg % 12;
  const int y = rem / 3, p = rem - y * 3;
  const int m0 = mt * 256, n0 = y * 256;

  const u16* wp = wt + (size_t)p * 1024 * 512;
  const float* bias = (p == 0) ? bq : (p == 1) ? bk : bv;
  u16* outp = (p == 0) ? qout : (p == 1) ? kout : vout;
  const float osc = (p == 0) ? 0.12751744116389548f : 1.0f;  // log2(e)/sqrt(128)

  const int tid = threadIdx.x, l = tid & 63, w = tid >> 6;
  const int lr = l & 15, lg = l >> 4;
  const int wr = w >> 2, wc = w & 3;   // 2 x 4 wave grid

  // hoisted staging addresses: 2048 chunks per matrix, 4/thread each
  // (XOR-chunk pre-swizzled source, linear LDS dest)
  const u16* asrc[4]; const u16* bsrc[4];
  unsigned adst[4], bdst[4];
#pragma unroll
  for (int c = 0; c < 4; ++c) {
    int ch = c * 512 + tid, row = ch >> 3, scc = (ch & 7) ^ (row & 7);
    asrc[c] = xb + (size_t)(m0 + row) * 512 + scc * 8;
    bsrc[c] = wp + (size_t)(n0 + row) * 512 + scc * 8;
    adst[c] = (unsigned)(ch * 16);
    bdst[c] = (unsigned)(32768 + ch * 16);
  }

  f32x4 acc[8][4] = {};

  // prologue: stage tile 0 into buf0
  {
    char* b0 = smb;
#pragma unroll
    for (int c = 0; c < 4; ++c) {
      gload16(asrc[c], b0 + adst[c]);
      gload16(bsrc[c], b0 + bdst[c]);
    }
  }
  __syncthreads();

  for (int t = 0; t < 8; ++t) {
    const char* cb = smb + (t & 1) * 65536;        // current buffer
    char* nb = smb + ((t + 1) & 1) * 65536;        // next buffer
    const bool pre = (t < 7);

#pragma unroll
    for (int ph = 0; ph < 4; ++ph) {
      if (pre) {   // issue 2 of next tile's loads (spread across phases)
        gload16(asrc[ph] + (t + 1) * 64, nb + adst[ph]);
        gload16(bsrc[ph] + (t + 1) * 64, nb + bdst[ph]);
      }
      const int fh = ph >> 1, kk = ph & 1;
      bfrag af[4], bf_[4];
#pragma unroll
      for (int fi = 0; fi < 4; ++fi) {
        int row = wr * 128 + (fh * 4 + fi) * 16 + lr;
        af[fi] = *(const bfrag*)(cb + row * 128 + (((kk * 4 + lg) ^ (row & 7)) * 16));
      }
#pragma unroll
      for (int fn = 0; fn < 4; ++fn) {
        int row = wc * 64 + fn * 16 + lr;
        bf_[fn] = *(const bfrag*)(cb + 32768 + row * 128 + (((kk * 4 + lg) ^ (row & 7)) * 16));
      }
      __builtin_amdgcn_s_setprio(1);
#pragma unroll
      for (int fi = 0; fi < 4; ++fi)
#pragma unroll
        for (int fn = 0; fn < 4; ++fn)
          acc[fh * 4 + fi][fn] = mfma16(af[fi], bf_[fn], acc[fh * 4 + fi][fn]);
      __builtin_amdgcn_s_setprio(0);
    }
    __syncthreads();   // drains vmcnt(0): next tile's loads (issued >=4 phases ago) landed
  }

  // epilogue: perm write  (h'=c>>7, c'=(c&127)*8+(j>>7), d=j&127)
#pragma unroll
  for (int fm = 0; fm < 8; ++fm) {
#pragma unroll
    for (int r = 0; r < 4; ++r) {
      int m = m0 + wr * 128 + fm * 16 + lg * 4 + r;
      int b = m >> 10, c = m & 1023;
      int gh = c >> 7;
#pragma unroll
      for (int fn = 0; fn < 4; ++fn) {
        int j = n0 + wc * 64 + fn * 16 + lr;
        float v = (acc[fm][fn][r] + bias[j]) * osc;
        int ii = ((c & 127) << 3) | (j >> 7);
        int d = j & 127;
        size_t idx = (((size_t)(b * 8 + gh) * 1024 + ii) << 7) | d;
        outp[idx] = f2bf(v);
      }
    }
  }
}

// ---------- fused flash attention (8-wave block, no-max softmax) ----------
// O = softmax(QK^T/sqrt(D))@V - V.  512 blocks (XCD-swizzled) x 512 threads;
// S^T = mfma32(K,Q); P = exp2(S') directly (bounded domain); in-register P^T
// via cvt_pk + permlane32_swap; O^T = mfma32(V^T,P^T); XOR-folded addressing.
__global__ __launch_bounds__(512, 2)
void attn_kernel(const u16* __restrict__ qp_all, const u16* __restrict__ kp_all,
                 const u16* __restrict__ vt_all, u16* __restrict__ attout) {
  __shared__ u16 smem[2 * 16384];
  char* smb = (char*)smem;

  const int bid = blockIdx.x;
  const int wg = (bid & 7) * 64 + (bid >> 3);
  const int bh = wg >> 2;
  const int qtp = wg & 3;

  const int tid = threadIdx.x, l = tid & 63, w = tid >> 6;   // w in 0..7
  const int q31 = l & 31, hi = l >> 5;

  const u16* qp  = qp_all + (size_t)bh * (Cn * Dn);
  const u16* kp  = kp_all + (size_t)bh * (Cn * Dn);
  const u16* vtp = vt_all + (size_t)bh * (Dn * Cn);
  const int qr0 = qtp * 256 + w * 32;    // wave's 32 q-rows within the head

  const unsigned LK = (unsigned)(q31 * 256) ^ (unsigned)((q31 & 15) * 16) ^ (unsigned)(hi * 16);
  const unsigned LV = 16384u ^ (unsigned)(q31 * 128) ^ (unsigned)((q31 & 7) * 16) ^ (unsigned)(hi * 16);

  const u16* ksrc[2]; const u16* vsrc[2];
  unsigned kdst[2], vdst[2];
#pragma unroll
  for (int c = 0; c < 2; ++c) {
    int ch = c * 512 + tid;
    int krow = ch >> 4, kscc = (ch & 15) ^ (krow & 15);
    ksrc[c] = kp + krow * 128 + kscc * 8;
    int vrow = ch >> 3, vscc = (ch & 7) ^ (vrow & 7);
    vsrc[c] = vtp + (size_t)vrow * 1024 + vscc * 8;
    kdst[c] = (unsigned)((c * 512 + w * 64) * 16);
    vdst[c] = 16384u + (unsigned)((c * 512 + w * 64) * 16);
  }
  auto stage = [&](int t2, unsigned bufb) {
#pragma unroll
    for (int c = 0; c < 2; ++c)
      gload16(ksrc[c] + (size_t)t2 * 8192, smb + (bufb ^ kdst[c]));
#pragma unroll
    for (int c = 0; c < 2; ++c)
      gload16(vsrc[c] + (size_t)t2 * 64, smb + (bufb ^ vdst[c]));
  };

  bfrag aq[8];
#pragma unroll
  for (int kk = 0; kk < 8; ++kk)
    aq[kk] = *(const bfrag*)(qp + (size_t)(qr0 + q31) * Dn + kk * 16 + hi * 8);

  f32x16 ot[4] = {};                 // O^T accumulator: col q=q31, rows d
  float lsum = 0.f;                  // per-lane HALF-sum of exp2 (combined at end)

  stage(0, 0);
  __syncthreads();

  unsigned bufb = 0;
  for (int t = 0; t < 16; ++t) {
    const unsigned nb = bufb ^ 32768u;
    if (t < 15) stage(t + 1, nb);    // lands during this iter's compute
    const unsigned LKb = LK ^ bufb;
    const unsigned LVb = LV ^ bufb;

    f32x16 st0 = {}, st1 = {};
    __builtin_amdgcn_s_setprio(1);
#pragma unroll
    for (int kk = 0; kk < 8; ++kk) {
      bfrag k0 = *(const bfrag*)(smb + (LKb ^ (unsigned)(kk * 32)));
      st0 = mfma32(k0, aq[kk], st0);
      bfrag k1 = *(const bfrag*)(smb + (LKb ^ (unsigned)(8192 + kk * 32)));
      st1 = mfma32(k1, aq[kk], st1);
    }
    __builtin_amdgcn_s_setprio(0);

    float rp[4] = {0.f, 0.f, 0.f, 0.f};
#pragma unroll
    for (int r = 0; r < 16; ++r) {
      float p0 = fexp2(st0[r]);
      st0[r] = p0;
      rp[r & 3] += p0;
    }
#pragma unroll
    for (int r = 0; r < 16; ++r) {
      float p1 = fexp2(st1[r]);
      st1[r] = p1;
      rp[r & 3] += p1;
    }
    lsum += (rp[0] + rp[1]) + (rp[2] + rp[3]);

    bfrag pb[4];
    {
      unsigned c0_[8], c1_[8];
#pragma unroll
      for (int m = 0; m < 8; ++m) {
        c0_[m] = cvtpk(st0[2 * m], st0[2 * m + 1]);
        c1_[m] = cvtpk(st1[2 * m], st1[2 * m + 1]);
      }
#pragma unroll
      for (int kkt = 0; kkt < 2; ++kkt) {
        unsigned a0 = c0_[4 * kkt + 0], b0 = c0_[4 * kkt + 2];
        unsigned a1 = c0_[4 * kkt + 1], b1 = c0_[4 * kkt + 3];
        asm("v_permlane32_swap_b32 %0, %1" : "+v"(a0), "+v"(b0));
        asm("v_permlane32_swap_b32 %0, %1" : "+v"(a1), "+v"(b1));
        u32x4 bw; bw.x = a0; bw.y = a1; bw.z = b0; bw.w = b1;
        pb[kkt] = __builtin_bit_cast(bfrag, bw);
      }
#pragma unroll
      for (int kkt = 0; kkt < 2; ++kkt) {
        unsigned a0 = c1_[4 * kkt + 0], b0 = c1_[4 * kkt + 2];
        unsigned a1 = c1_[4 * kkt + 1], b1 = c1_[4 * kkt + 3];
        asm("v_permlane32_swap_b32 %0, %1" : "+v"(a0), "+v"(b0));
        asm("v_permlane32_swap_b32 %0, %1" : "+v"(a1), "+v"(b1));
        u32x4 bw; bw.x = a0; bw.y = a1; bw.z = b0; bw.w = b1;
        pb[2 + kkt] = __builtin_bit_cast(bfrag, bw);
      }
    }

    __builtin_amdgcn_s_setprio(1);
#pragma unroll
    for (int kk = 0; kk < 4; ++kk) {
#pragma unroll
      for (int dt = 0; dt < 4; ++dt) {
        bfrag vf = *(const bfrag*)(smb + (LVb ^ (unsigned)(dt * 4096 + kk * 32)));
        ot[dt] = mfma32(vf, pb[kk], ot[dt]);
      }
    }
    __builtin_amdgcn_s_setprio(0);
    __syncthreads();  // drains vmcnt(0): prefetch (issued at iter top) landed
    bufb = nb;
  }

  // ---- epilogue: combine half-sums, (O^T/l - V^T[d][c1]) -> LDS -> write ----
  const float lfull = lsum + __shfl_xor(lsum, 32, 64);
  const float linv = 1.f / lfull;
  const int c1 = qr0 + q31;
  u16* my = smem + w * 4096;
#pragma unroll
  for (int dt = 0; dt < 4; ++dt)
#pragma unroll
    for (int rp2 = 0; rp2 < 8; ++rp2) {
      int reg = 2 * rp2;
      int d = dt * 32 + (reg & 3) + 8 * (reg >> 2) + 4 * hi;
      float v0 = bf2f(vtp[((size_t)d << 10) | c1]);
      float v1 = bf2f(vtp[((size_t)(d + 1) << 10) | c1]);
      unsigned pk = cvtpk(ot[dt][reg] * linv - v0, ot[dt][reg + 1] * linv - v1);
      *(unsigned*)&my[q31 * 128 + (((d >> 3) ^ (q31 & 7)) << 3) + (d & 7)] = pk;
    }
  const int b = bh >> 3, h = bh & 7;
#pragma unroll
  for (int it = 0; it < 8; ++it) {
    int rowq = it * 4 + (l >> 4);
    int ch = l & 15;
    u16x8 rd = *(const u16x8*)&my[rowq * 128 + ((ch ^ (rowq & 7))) * 8];
    int cg = qr0 + rowq;
    *(u16x8*)&attout[(((size_t)(b * 1024 + cg)) * 8 + h) * 128 + ch * 8] = rd;
  }
}

// ---------- output GEMM: [16384][1024] @ [1024][128] + bias -> f32 ----------
__global__ void out_gemm(const u16* __restrict__ A, const u16* __restrict__ Bt,
                         const float* __restrict__ bias, float* __restrict__ out) {
  __shared__ u16 As[32 * 64];
  __shared__ u16 Bs[128 * 64];
  const int m0 = blockIdx.x * 32;
  const int tid = threadIdx.x, l = tid & 63, w = tid >> 6;
  const int lr = l & 15, lg = l >> 4;
  f32x4 acc[2][2] = {};

  for (int kt = 0; kt < 1024; kt += 64) {
    {   // As: 256 chunks, 1/thread
      int ch = w * 64 + l;
      int row = ch >> 3, scc = (ch & 7) ^ (row & 7);
      gload16(A + (size_t)(m0 + row) * 1024 + kt + scc * 8, &As[(w * 64) * 8]);
    }
#pragma unroll
    for (int i = 0; i < 4; ++i) {   // Bs: 1024 chunks, 4/thread
      int chb = (i * 4 + w) * 64;
      int ch = chb + l;
      int row = ch >> 3, scc = (ch & 7) ^ (row & 7);
      gload16(Bt + (size_t)row * 1024 + kt + scc * 8, &Bs[chb * 8]);
    }
    __syncthreads();
#pragma unroll
    for (int kk = 0; kk < 2; ++kk) {
      bfrag af[2], bf_[2];
#pragma unroll
      for (int fm = 0; fm < 2; ++fm) {
        int row = fm * 16 + lr;
        int off = (kk * 4 + lg) ^ (row & 7);
        af[fm] = *(const bfrag*)&As[row * 64 + off * 8];
      }
#pragma unroll
      for (int fn = 0; fn < 2; ++fn) {
        int row = w * 32 + fn * 16 + lr;
        int off = (kk * 4 + lg) ^ (row & 7);
        bf_[fn] = *(const bfrag*)&Bs[row * 64 + off * 8];
      }
#pragma unroll
      for (int fm = 0; fm < 2; ++fm)
#pragma unroll
        for (int fn = 0; fn < 2; ++fn)
          acc[fm][fn] = mfma16(af[fm], bf_[fn], acc[fm][fn]);
    }
    __syncthreads();
  }
#pragma unroll
  for (int fm = 0; fm < 2; ++fm)
#pragma unroll
    for (int r = 0; r < 4; ++r) {
      int m = m0 + fm * 16 + lg * 4 + r;
#pragma unroll
      for (int fn = 0; fn < 2; ++fn) {
        int j = w * 32 + fn * 16 + lr;
        out[(size_t)m * 128 + j] = acc[fm][fn][r] + bias[j];
      }
    }
}

// ---------- launch ----------
extern "C" void kernel_launch(void* const* d_in, const int* in_sizes, int n_in,
                              void* d_out, int out_size, void* d_ws, size_t ws_size,
                              hipStream_t stream) {
  const float* x   = (const float*)d_in[0];
  const float* Wk  = (const float*)d_in[1];
  const float* bk_ = (const float*)d_in[2];
  const float* Wq  = (const float*)d_in[3];
  const float* bq_ = (const float*)d_in[4];
  const float* Wv  = (const float*)d_in[5];
  const float* bv_ = (const float*)d_in[6];
  const float* Ww0 = (const float*)d_in[7];
  const float* bw0 = (const float*)d_in[8];
  float* out = (float*)d_out;

  char* ws = (char*)d_ws;
  u16* xb   = (u16*)(ws + OFF_XB);
  u16* wt   = (u16*)(ws + OFF_WT);
  u16* w0t  = (u16*)(ws + OFF_W0T);
  u16* qpm  = (u16*)(ws + OFF_Q);
  u16* kpm  = (u16*)(ws + OFF_K);
  u16* vpm  = (u16*)(ws + OFF_V);   // becomes V^T after vtrans
  u16* attb = (u16*)(ws + OFF_ATT); // perm-V staging, then attn output

  // prep: cast x, transpose+cast weights (3 fused + w0)
  cvt_bf16<<<(M1 * Fn / 4 + 255) / 256, 256, 0, stream>>>(x, xb, M1 * Fn);
  dim3 tb(32, 8);
  transpose_cvt3<<<dim3(32, 16, 3), tb, 0, stream>>>(Wq, Wk, Wv, wt);
  transpose_cvt<<<dim3(4, 32), tb, 0, stream>>>(Ww0, w0t, 1024, 128);

  // projections: Q,K -> perm layout; perm-V -> attb (scratch); 256^2 phased
  qkv_gemm<<<dim3(768), 512, 0, stream>>>(xb, wt, bq_, bk_, bv_, qpm, kpm, attb);

  // per-head transpose perm-V (attb) -> V^T (vpm)
  vtrans<<<dim3(4, 32, 128), tb, 0, stream>>>(attb, vpm);

  // fused attention (softmax - I folded as O = P@V - V), XCD-swizzled grid
  attn_kernel<<<dim3(512), 512, 0, stream>>>(qpm, kpm, vpm, attb);

  // output projection (f32 out + bias)
  out_gemm<<<512, 256, 0, stream>>>(attb, w0t, bw0, out);
}

// Round 16
// 179.062 us; speedup vs baseline: 1.0204x; 1.0204x over previous
//
#include <hip/hip_runtime.h>
#include <hip/hip_bf16.h>
#include <cstdint>
#include <cstddef>

// ---------- types ----------
using u16 = unsigned short;
typedef __attribute__((ext_vector_type(4))) float f32x4;
typedef __attribute__((ext_vector_type(16))) float f32x16;
typedef __attribute__((ext_vector_type(8))) unsigned short u16x8;
typedef __attribute__((ext_vector_type(4))) unsigned short u16x4;
typedef __attribute__((ext_vector_type(2))) unsigned short u16x2;
typedef __attribute__((ext_vector_type(4))) unsigned int u32x4;
typedef __bf16 bfrag __attribute__((ext_vector_type(8)));   // 8 bf16 = 4 VGPR MFMA operand

constexpr int Hn = 8, Cn = 1024, Dn = 128, Fn = 512, Bn = 16;
constexpr int M1 = Bn * Cn;  // 16384 rows of x / att_out

// workspace layout (bytes)
constexpr size_t OFF_XB  = 0;                                  // x bf16 [16384][512]
constexpr size_t SZ_XB   = (size_t)M1 * Fn * 2;                // 16 MiB
constexpr size_t OFF_WT  = OFF_XB + SZ_XB;                     // Wt bf16 [3][1024][512] (q,k,v)
constexpr size_t SZ_WT   = 3ull * 1024 * 512 * 2;              // 3 MiB
constexpr size_t OFF_W0T = OFF_WT + SZ_WT;                     // Ww0^T bf16 [128][1024]
constexpr size_t SZ_W0T  = 128ull * 1024 * 2;
constexpr size_t OFF_Q   = OFF_W0T + SZ_W0T;                   // q perm [16][8][1024][128] bf16
constexpr size_t SZ_P    = (size_t)Bn * Hn * Cn * Dn * 2;      // 32 MiB each
constexpr size_t OFF_K   = OFF_Q + SZ_P;
constexpr size_t OFF_V   = OFF_K + SZ_P;                       // V^T: [bh][128 d][1024 c]
constexpr size_t OFF_ATT = OFF_V + SZ_P;                       // vals2 bf16 [16384][1024]
// NOTE buffer reuse: qkv writes perm-V into OFF_ATT (dead until attn output);
// vtrans transposes OFF_ATT -> OFF_V; attn then overwrites OFF_ATT.

// ---------- helpers ----------
__device__ __forceinline__ float bf2f(u16 u) {
  unsigned int x = ((unsigned int)u) << 16;
  return __builtin_bit_cast(float, x);
}
__device__ __forceinline__ u16 f2bf(float f) {
  unsigned int u = __builtin_bit_cast(unsigned int, f);
  u += 0x7fffu + ((u >> 16) & 1u);   // RNE
  return (u16)(u >> 16);
}
__device__ __forceinline__ f32x4 mfma16(bfrag a, bfrag b, f32x4 c) {
  return __builtin_amdgcn_mfma_f32_16x16x32_bf16(a, b, c, 0, 0, 0);
}
__device__ __forceinline__ f32x16 mfma32(bfrag a, bfrag b, f32x16 c) {
  return __builtin_amdgcn_mfma_f32_32x32x16_bf16(a, b, c, 0, 0, 0);
}
// async 16B global->LDS; lds base must be wave-uniform (lane*16 auto-offset)
__device__ __forceinline__ void gload16(const void* g, void* lds) {
  __builtin_amdgcn_global_load_lds(
      (const __attribute__((address_space(1))) unsigned int*)g,
      (__attribute__((address_space(3))) unsigned int*)lds, 16, 0, 0);
}
__device__ __forceinline__ unsigned cvtpk(float lo, float hi) {
  unsigned r;
  asm("v_cvt_pk_bf16_f32 %0, %1, %2" : "=v"(r) : "v"(lo), "v"(hi));
  return r;
}
// raw HW exp2 (1 instr; valid here: |x| < ~2 by construction)
__device__ __forceinline__ float fexp2(float x) {
  float r;
  asm("v_exp_f32 %0, %1" : "=v"(r) : "v"(x));
  return r;
}

// ---------- prep kernels ----------
// 8 elems/thread: 2 x float4 in, 1 x u16x8 out
__global__ void cvt_bf16(const float* __restrict__ in, u16* __restrict__ out, int n) {
  int idx = (blockIdx.x * blockDim.x + threadIdx.x) * 8;
  if (idx < n) {
    float4 v0 = *(const float4*)(in + idx);
    float4 v1 = *(const float4*)(in + idx + 4);
    u16x8 o;
    o[0] = f2bf(v0.x); o[1] = f2bf(v0.y); o[2] = f2bf(v0.z); o[3] = f2bf(v0.w);
    o[4] = f2bf(v1.x); o[5] = f2bf(v1.y); o[6] = f2bf(v1.z); o[7] = f2bf(v1.w);
    *(u16x8*)(out + idx) = o;
  }
}

// in [R][Cc] f32 -> out [Cc][R] bf16 ; block (32,8), grid (Cc/32, R/32)
__global__ void transpose_cvt(const float* __restrict__ in, u16* __restrict__ out,
                              int R, int Cc) {
  __shared__ float tile[32][33];
  int c0 = blockIdx.x * 32, r0 = blockIdx.y * 32;
  int tx = threadIdx.x, ty = threadIdx.y;
#pragma unroll
  for (int i = 0; i < 4; ++i)
    tile[ty + i * 8][tx] = in[(size_t)(r0 + ty + i * 8) * Cc + c0 + tx];
  __syncthreads();
#pragma unroll
  for (int i = 0; i < 4; ++i)
    out[(size_t)(c0 + ty + i * 8) * R + r0 + tx] = f2bf(tile[tx][ty + i * 8]);
}

// fused: the three 512x1024 weight transposes in one launch (z = which matrix)
__global__ void transpose_cvt3(const float* __restrict__ W0, const float* __restrict__ W1,
                               const float* __restrict__ W2, u16* __restrict__ out) {
  __shared__ float tile[32][33];
  const int z = blockIdx.z;
  const float* in = (z == 0) ? W0 : (z == 1) ? W1 : W2;
  u16* op = out + (size_t)z * 1024 * 512;
  int c0 = blockIdx.x * 32, r0 = blockIdx.y * 32;
  int tx = threadIdx.x, ty = threadIdx.y;
#pragma unroll
  for (int i = 0; i < 4; ++i)
    tile[ty + i * 8][tx] = in[(size_t)(r0 + ty + i * 8) * 1024 + c0 + tx];
  __syncthreads();
#pragma unroll
  for (int i = 0; i < 4; ++i)
    op[(size_t)(c0 + ty + i * 8) * 512 + r0 + tx] = f2bf(tile[tx][ty + i * 8]);
}

// per-head V transpose: in [bh][1024 c'][128 d] u16 -> out [bh][128 d][1024 c']
// 64x64 tiles, u16x2 loads AND stores (4 B/lane); block (32,8),
// grid (2 d-tiles, 16 c-tiles, 128 bh).  LDS 64x65 u16 (odd pitch: conflict-free).
__global__ void vtrans(const u16* __restrict__ in, u16* __restrict__ out) {
  __shared__ u16 tile[64][65];
  int d0 = blockIdx.x * 64, c0 = blockIdx.y * 64, bh = blockIdx.z;
  const u16* ip = in + (size_t)bh * (Cn * Dn);
  u16* op = out + (size_t)bh * (Dn * Cn);
  int tx = threadIdx.x, ty = threadIdx.y;
#pragma unroll
  for (int i = 0; i < 8; ++i) {
    int r = ty + i * 8;
    u16x2 v = *(const u16x2*)&ip[(size_t)(c0 + r) * Dn + d0 + tx * 2];
    tile[r][tx * 2] = v.x;
    tile[r][tx * 2 + 1] = v.y;
  }
  __syncthreads();
#pragma unroll
  for (int i = 0; i < 8; ++i) {
    int rr = ty + i * 8;               // output d-row
    u16x2 v;
    v.x = tile[tx * 2][rr];
    v.y = tile[tx * 2 + 1][rr];
    *(u16x2*)&op[(size_t)(d0 + rr) * Cn + c0 + tx * 2] = v;
  }
}

// ---------- QKV projection GEMM (R12-proven: 128x128, 256 thr, 2-barrier) ----------
// Q output pre-scaled by log2(e)/sqrt(D); outputs in perm layout [bh][c'][d];
// V transposed afterwards by vtrans.  Structural rewrites (counted-vmcnt 3-buf,
// XCD swizzle, 256^2 phased) all regressed or were null (R13-R15) -- this is
// the m97-structure kernel that produced the best total (178.25, R12).
__global__ void qkv_gemm(const u16* __restrict__ xb, const u16* __restrict__ wt,
                         const float* __restrict__ bq, const float* __restrict__ bk,
                         const float* __restrict__ bv,
                         u16* __restrict__ qout, u16* __restrict__ kout,
                         u16* __restrict__ vout) {
  __shared__ u16 As[128 * 64];
  __shared__ u16 Bs[128 * 64];
  const int m0 = blockIdx.x * 128;
  const int n0 = blockIdx.y * 128;
  const int p  = blockIdx.z;
  const u16* wp = wt + (size_t)p * 1024 * 512;
  const float* bias = (p == 0) ? bq : (p == 1) ? bk : bv;
  u16* outp = (p == 0) ? qout : (p == 1) ? kout : vout;
  const float osc = (p == 0) ? 0.12751744116389548f : 1.0f;  // log2(e)/sqrt(128)

  const int tid = threadIdx.x, l = tid & 63, w = tid >> 6;
  const int lr = l & 15, lg = l >> 4;
  const int wr = w >> 1, wc = w & 1;

  f32x4 acc[4][4] = {};

  for (int kt = 0; kt < Fn; kt += 64) {
#pragma unroll
    for (int i = 0; i < 4; ++i) {
      int chb = (i * 4 + w) * 64;
      int ch = chb + l;
      int row = ch >> 3, scc = (ch & 7) ^ (row & 7);
      gload16(xb + (size_t)(m0 + row) * Fn + kt + scc * 8, &As[chb * 8]);
    }
#pragma unroll
    for (int i = 0; i < 4; ++i) {
      int chb = (i * 4 + w) * 64;
      int ch = chb + l;
      int row = ch >> 3, scc = (ch & 7) ^ (row & 7);
      gload16(wp + (size_t)(n0 + row) * Fn + kt + scc * 8, &Bs[chb * 8]);
    }
    __syncthreads();
#pragma unroll
    for (int kk = 0; kk < 2; ++kk) {
      bfrag af[4], bf_[4];
#pragma unroll
      for (int fm = 0; fm < 4; ++fm) {
        int row = wr * 64 + fm * 16 + lr;
        int off = (kk * 4 + lg) ^ (row & 7);
        af[fm] = *(const bfrag*)&As[row * 64 + off * 8];
      }
#pragma unroll
      for (int fn = 0; fn < 4; ++fn) {
        int row = wc * 64 + fn * 16 + lr;
        int off = (kk * 4 + lg) ^ (row & 7);
        bf_[fn] = *(const bfrag*)&Bs[row * 64 + off * 8];
      }
#pragma unroll
      for (int fm = 0; fm < 4; ++fm)
#pragma unroll
        for (int fn = 0; fn < 4; ++fn)
          acc[fm][fn] = mfma16(af[fm], bf_[fn], acc[fm][fn]);
    }
    __syncthreads();
  }

  // epilogue: perm write  (h'=c>>7, c'=(c&127)*8+(j>>7), d=j&127)
#pragma unroll
  for (int fm = 0; fm < 4; ++fm) {
#pragma unroll
    for (int r = 0; r < 4; ++r) {
      int m = m0 + wr * 64 + fm * 16 + lg * 4 + r;
      int b = m >> 10, c = m & 1023;
      int gh = c >> 7;
#pragma unroll
      for (int fn = 0; fn < 4; ++fn) {
        int j = n0 + wc * 64 + fn * 16 + lr;
        float v = (acc[fm][fn][r] + bias[j]) * osc;
        int ii = ((c & 127) << 3) | (j >> 7);
        int d = j & 127;
        size_t idx = (((size_t)(b * 8 + gh) * 1024 + ii) << 7) | d;
        outp[idx] = f2bf(v);
      }
    }
  }
}

// ---------- fused flash attention (8-wave block, no-max softmax) ----------
// O = softmax(QK^T/sqrt(D))@V - V.  512 blocks (XCD-swizzled) x 512 threads;
// S^T = mfma32(K,Q); P = exp2(S') directly (bounded domain); in-register P^T
// via cvt_pk + permlane32_swap; O^T = mfma32(V^T,P^T); XOR-folded addressing.
__global__ __launch_bounds__(512, 2)
void attn_kernel(const u16* __restrict__ qp_all, const u16* __restrict__ kp_all,
                 const u16* __restrict__ vt_all, u16* __restrict__ attout) {
  __shared__ u16 smem[2 * 16384];
  char* smb = (char*)smem;

  const int bid = blockIdx.x;
  const int wg = (bid & 7) * 64 + (bid >> 3);
  const int bh = wg >> 2;
  const int qtp = wg & 3;

  const int tid = threadIdx.x, l = tid & 63, w = tid >> 6;   // w in 0..7
  const int q31 = l & 31, hi = l >> 5;

  const u16* qp  = qp_all + (size_t)bh * (Cn * Dn);
  const u16* kp  = kp_all + (size_t)bh * (Cn * Dn);
  const u16* vtp = vt_all + (size_t)bh * (Dn * Cn);
  const int qr0 = qtp * 256 + w * 32;    // wave's 32 q-rows within the head

  const unsigned LK = (unsigned)(q31 * 256) ^ (unsigned)((q31 & 15) * 16) ^ (unsigned)(hi * 16);
  const unsigned LV = 16384u ^ (unsigned)(q31 * 128) ^ (unsigned)((q31 & 7) * 16) ^ (unsigned)(hi * 16);

  const u16* ksrc[2]; const u16* vsrc[2];
  unsigned kdst[2], vdst[2];
#pragma unroll
  for (int c = 0; c < 2; ++c) {
    int ch = c * 512 + tid;
    int krow = ch >> 4, kscc = (ch & 15) ^ (krow & 15);
    ksrc[c] = kp + krow * 128 + kscc * 8;
    int vrow = ch >> 3, vscc = (ch & 7) ^ (vrow & 7);
    vsrc[c] = vtp + (size_t)vrow * 1024 + vscc * 8;
    kdst[c] = (unsigned)((c * 512 + w * 64) * 16);
    vdst[c] = 16384u + (unsigned)((c * 512 + w * 64) * 16);
  }
  auto stage = [&](int t2, unsigned bufb) {
#pragma unroll
    for (int c = 0; c < 2; ++c)
      gload16(ksrc[c] + (size_t)t2 * 8192, smb + (bufb ^ kdst[c]));
#pragma unroll
    for (int c = 0; c < 2; ++c)
      gload16(vsrc[c] + (size_t)t2 * 64, smb + (bufb ^ vdst[c]));
  };

  bfrag aq[8];
#pragma unroll
  for (int kk = 0; kk < 8; ++kk)
    aq[kk] = *(const bfrag*)(qp + (size_t)(qr0 + q31) * Dn + kk * 16 + hi * 8);

  f32x16 ot[4] = {};                 // O^T accumulator: col q=q31, rows d
  float lsum = 0.f;                  // per-lane HALF-sum of exp2 (combined at end)

  stage(0, 0);
  __syncthreads();

  unsigned bufb = 0;
  for (int t = 0; t < 16; ++t) {
    const unsigned nb = bufb ^ 32768u;
    if (t < 15) stage(t + 1, nb);    // lands during this iter's compute
    const unsigned LKb = LK ^ bufb;
    const unsigned LVb = LV ^ bufb;

    f32x16 st0 = {}, st1 = {};
    __builtin_amdgcn_s_setprio(1);
#pragma unroll
    for (int kk = 0; kk < 8; ++kk) {
      bfrag k0 = *(const bfrag*)(smb + (LKb ^ (unsigned)(kk * 32)));
      st0 = mfma32(k0, aq[kk], st0);
      bfrag k1 = *(const bfrag*)(smb + (LKb ^ (unsigned)(8192 + kk * 32)));
      st1 = mfma32(k1, aq[kk], st1);
    }
    __builtin_amdgcn_s_setprio(0);

    float rp[4] = {0.f, 0.f, 0.f, 0.f};
#pragma unroll
    for (int r = 0; r < 16; ++r) {
      float p0 = fexp2(st0[r]);
      st0[r] = p0;
      rp[r & 3] += p0;
    }
#pragma unroll
    for (int r = 0; r < 16; ++r) {
      float p1 = fexp2(st1[r]);
      st1[r] = p1;
      rp[r & 3] += p1;
    }
    lsum += (rp[0] + rp[1]) + (rp[2] + rp[3]);

    bfrag pb[4];
    {
      unsigned c0_[8], c1_[8];
#pragma unroll
      for (int m = 0; m < 8; ++m) {
        c0_[m] = cvtpk(st0[2 * m], st0[2 * m + 1]);
        c1_[m] = cvtpk(st1[2 * m], st1[2 * m + 1]);
      }
#pragma unroll
      for (int kkt = 0; kkt < 2; ++kkt) {
        unsigned a0 = c0_[4 * kkt + 0], b0 = c0_[4 * kkt + 2];
        unsigned a1 = c0_[4 * kkt + 1], b1 = c0_[4 * kkt + 3];
        asm("v_permlane32_swap_b32 %0, %1" : "+v"(a0), "+v"(b0));
        asm("v_permlane32_swap_b32 %0, %1" : "+v"(a1), "+v"(b1));
        u32x4 bw; bw.x = a0; bw.y = a1; bw.z = b0; bw.w = b1;
        pb[kkt] = __builtin_bit_cast(bfrag, bw);
      }
#pragma unroll
      for (int kkt = 0; kkt < 2; ++kkt) {
        unsigned a0 = c1_[4 * kkt + 0], b0 = c1_[4 * kkt + 2];
        unsigned a1 = c1_[4 * kkt + 1], b1 = c1_[4 * kkt + 3];
        asm("v_permlane32_swap_b32 %0, %1" : "+v"(a0), "+v"(b0));
        asm("v_permlane32_swap_b32 %0, %1" : "+v"(a1), "+v"(b1));
        u32x4 bw; bw.x = a0; bw.y = a1; bw.z = b0; bw.w = b1;
        pb[2 + kkt] = __builtin_bit_cast(bfrag, bw);
      }
    }

    __builtin_amdgcn_s_setprio(1);
#pragma unroll
    for (int kk = 0; kk < 4; ++kk) {
#pragma unroll
      for (int dt = 0; dt < 4; ++dt) {
        bfrag vf = *(const bfrag*)(smb + (LVb ^ (unsigned)(dt * 4096 + kk * 32)));
        ot[dt] = mfma32(vf, pb[kk], ot[dt]);
      }
    }
    __builtin_amdgcn_s_setprio(0);
    __syncthreads();  // drains vmcnt(0): prefetch (issued at iter top) landed
    bufb = nb;
  }

  // ---- epilogue: combine half-sums, (O^T/l - V^T[d][c1]) -> LDS -> write ----
  const float lfull = lsum + __shfl_xor(lsum, 32, 64);
  const float linv = 1.f / lfull;
  const int c1 = qr0 + q31;
  u16* my = smem + w * 4096;
#pragma unroll
  for (int dt = 0; dt < 4; ++dt)
#pragma unroll
    for (int rp2 = 0; rp2 < 8; ++rp2) {
      int reg = 2 * rp2;
      int d = dt * 32 + (reg & 3) + 8 * (reg >> 2) + 4 * hi;
      float v0 = bf2f(vtp[((size_t)d << 10) | c1]);
      float v1 = bf2f(vtp[((size_t)(d + 1) << 10) | c1]);
      unsigned pk = cvtpk(ot[dt][reg] * linv - v0, ot[dt][reg + 1] * linv - v1);
      *(unsigned*)&my[q31 * 128 + (((d >> 3) ^ (q31 & 7)) << 3) + (d & 7)] = pk;
    }
  const int b = bh >> 3, h = bh & 7;
#pragma unroll
  for (int it = 0; it < 8; ++it) {
    int rowq = it * 4 + (l >> 4);
    int ch = l & 15;
    u16x8 rd = *(const u16x8*)&my[rowq * 128 + ((ch ^ (rowq & 7))) * 8];
    int cg = qr0 + rowq;
    *(u16x8*)&attout[(((size_t)(b * 1024 + cg)) * 8 + h) * 128 + ch * 8] = rd;
  }
}

// ---------- output GEMM: [16384][1024] @ [1024][128] + bias -> f32 ----------
__global__ void out_gemm(const u16* __restrict__ A, const u16* __restrict__ Bt,
                         const float* __restrict__ bias, float* __restrict__ out) {
  __shared__ u16 As[32 * 64];
  __shared__ u16 Bs[128 * 64];
  const int m0 = blockIdx.x * 32;
  const int tid = threadIdx.x, l = tid & 63, w = tid >> 6;
  const int lr = l & 15, lg = l >> 4;
  f32x4 acc[2][2] = {};

  for (int kt = 0; kt < 1024; kt += 64) {
    {   // As: 256 chunks, 1/thread
      int ch = w * 64 + l;
      int row = ch >> 3, scc = (ch & 7) ^ (row & 7);
      gload16(A + (size_t)(m0 + row) * 1024 + kt + scc * 8, &As[(w * 64) * 8]);
    }
#pragma unroll
    for (int i = 0; i < 4; ++i) {   // Bs: 1024 chunks, 4/thread
      int chb = (i * 4 + w) * 64;
      int ch = chb + l;
      int row = ch >> 3, scc = (ch & 7) ^ (row & 7);
      gload16(Bt + (size_t)row * 1024 + kt + scc * 8, &Bs[chb * 8]);
    }
    __syncthreads();
#pragma unroll
    for (int kk = 0; kk < 2; ++kk) {
      bfrag af[2], bf_[2];
#pragma unroll
      for (int fm = 0; fm < 2; ++fm) {
        int row = fm * 16 + lr;
        int off = (kk * 4 + lg) ^ (row & 7);
        af[fm] = *(const bfrag*)&As[row * 64 + off * 8];
      }
#pragma unroll
      for (int fn = 0; fn < 2; ++fn) {
        int row = w * 32 + fn * 16 + lr;
        int off = (kk * 4 + lg) ^ (row & 7);
        bf_[fn] = *(const bfrag*)&Bs[row * 64 + off * 8];
      }
#pragma unroll
      for (int fm = 0; fm < 2; ++fm)
#pragma unroll
        for (int fn = 0; fn < 2; ++fn)
          acc[fm][fn] = mfma16(af[fm], bf_[fn], acc[fm][fn]);
    }
    __syncthreads();
  }
#pragma unroll
  for (int fm = 0; fm < 2; ++fm)
#pragma unroll
    for (int r = 0; r < 4; ++r) {
      int m = m0 + fm * 16 + lg * 4 + r;
#pragma unroll
      for (int fn = 0; fn < 2; ++fn) {
        int j = w * 32 + fn * 16 + lr;
        out[(size_t)m * 128 + j] = acc[fm][fn][r] + bias[j];
      }
    }
}

// ---------- launch ----------
extern "C" void kernel_launch(void* const* d_in, const int* in_sizes, int n_in,
                              void* d_out, int out_size, void* d_ws, size_t ws_size,
                              hipStream_t stream) {
  const float* x   = (const float*)d_in[0];
  const float* Wk  = (const float*)d_in[1];
  const float* bk_ = (const float*)d_in[2];
  const float* Wq  = (const float*)d_in[3];
  const float* bq_ = (const float*)d_in[4];
  const float* Wv  = (const float*)d_in[5];
  const float* bv_ = (const float*)d_in[6];
  const float* Ww0 = (const float*)d_in[7];
  const float* bw0 = (const float*)d_in[8];
  float* out = (float*)d_out;

  char* ws = (char*)d_ws;
  u16* xb   = (u16*)(ws + OFF_XB);
  u16* wt   = (u16*)(ws + OFF_WT);
  u16* w0t  = (u16*)(ws + OFF_W0T);
  u16* qpm  = (u16*)(ws + OFF_Q);
  u16* kpm  = (u16*)(ws + OFF_K);
  u16* vpm  = (u16*)(ws + OFF_V);   // becomes V^T after vtrans
  u16* attb = (u16*)(ws + OFF_ATT); // perm-V staging, then attn output

  // prep: cast x (8/thread), transpose+cast weights (3 fused + w0)
  cvt_bf16<<<(M1 * Fn / 8 + 255) / 256, 256, 0, stream>>>(x, xb, M1 * Fn);
  dim3 tb(32, 8);
  transpose_cvt3<<<dim3(32, 16, 3), tb, 0, stream>>>(Wq, Wk, Wv, wt);
  transpose_cvt<<<dim3(4, 32), tb, 0, stream>>>(Ww0, w0t, 1024, 128);

  // projections: Q,K -> perm layout; perm-V -> attb (scratch)  [R12 config]
  qkv_gemm<<<dim3(128, 8, 3), 256, 0, stream>>>(xb, wt, bq_, bk_, bv_, qpm, kpm, attb);

  // per-head transpose perm-V (attb) -> V^T (vpm), 4 B/lane
  vtrans<<<dim3(2, 16, 128), tb, 0, stream>>>(attb, vpm);

  // fused attention (softmax - I folded as O = P@V - V), XCD-swizzled grid
  attn_kernel<<<dim3(512), 512, 0, stream>>>(qpm, kpm, vpm, attb);

  // output projection (f32 out + bias)
  out_gemm<<<512, 256, 0, stream>>>(attb, w0t, bw0, out);
}

// Round 17
// 176.518 us; speedup vs baseline: 1.0351x; 1.0144x over previous
//
#include <hip/hip_runtime.h>
#include <hip/hip_bf16.h>
#include <cstdint>
#include <cstddef>

// ---------- types ----------
using u16 = unsigned short;
typedef __attribute__((ext_vector_type(4))) float f32x4;
typedef __attribute__((ext_vector_type(16))) float f32x16;
typedef __attribute__((ext_vector_type(8))) unsigned short u16x8;
typedef __attribute__((ext_vector_type(4))) unsigned short u16x4;
typedef __attribute__((ext_vector_type(2))) unsigned short u16x2;
typedef __attribute__((ext_vector_type(4))) unsigned int u32x4;
typedef __bf16 bfrag __attribute__((ext_vector_type(8)));   // 8 bf16 = 4 VGPR MFMA operand

constexpr int Hn = 8, Cn = 1024, Dn = 128, Fn = 512, Bn = 16;
constexpr int M1 = Bn * Cn;  // 16384 rows of x / att_out

// workspace layout (bytes)
constexpr size_t OFF_XB  = 0;                                  // x bf16 [16384][512]
constexpr size_t SZ_XB   = (size_t)M1 * Fn * 2;                // 16 MiB
constexpr size_t OFF_WT  = OFF_XB + SZ_XB;                     // Wt bf16 [3][1024][512] (q,k,v)
constexpr size_t SZ_WT   = 3ull * 1024 * 512 * 2;              // 3 MiB
constexpr size_t OFF_W0T = OFF_WT + SZ_WT;                     // Ww0^T bf16 [128][1024]
constexpr size_t SZ_W0T  = 128ull * 1024 * 2;
constexpr size_t OFF_Q   = OFF_W0T + SZ_W0T;                   // q perm [16][8][1024][128] bf16
constexpr size_t SZ_P    = (size_t)Bn * Hn * Cn * Dn * 2;      // 32 MiB each
constexpr size_t OFF_K   = OFF_Q + SZ_P;
constexpr size_t OFF_V   = OFF_K + SZ_P;                       // Vt2: [bh][y][128 d][128 k], c'=8k+y
constexpr size_t OFF_ATT = OFF_V + SZ_P;                       // vals2 bf16 [16384][1024]

// ---------- helpers ----------
__device__ __forceinline__ float bf2f(u16 u) {
  unsigned int x = ((unsigned int)u) << 16;
  return __builtin_bit_cast(float, x);
}
__device__ __forceinline__ u16 f2bf(float f) {
  unsigned int u = __builtin_bit_cast(unsigned int, f);
  u += 0x7fffu + ((u >> 16) & 1u);   // RNE
  return (u16)(u >> 16);
}
__device__ __forceinline__ f32x4 mfma16(bfrag a, bfrag b, f32x4 c) {
  return __builtin_amdgcn_mfma_f32_16x16x32_bf16(a, b, c, 0, 0, 0);
}
__device__ __forceinline__ f32x16 mfma32(bfrag a, bfrag b, f32x16 c) {
  return __builtin_amdgcn_mfma_f32_32x32x16_bf16(a, b, c, 0, 0, 0);
}
// async 16B global->LDS; lds base must be wave-uniform (lane*16 auto-offset)
__device__ __forceinline__ void gload16(const void* g, void* lds) {
  __builtin_amdgcn_global_load_lds(
      (const __attribute__((address_space(1))) unsigned int*)g,
      (__attribute__((address_space(3))) unsigned int*)lds, 16, 0, 0);
}
__device__ __forceinline__ unsigned cvtpk(float lo, float hi) {
  unsigned r;
  asm("v_cvt_pk_bf16_f32 %0, %1, %2" : "=v"(r) : "v"(lo), "v"(hi));
  return r;
}
// raw HW exp2 (1 instr; valid here: |x| < ~2 by construction)
__device__ __forceinline__ float fexp2(float x) {
  float r;
  asm("v_exp_f32 %0, %1" : "=v"(r) : "v"(x));
  return r;
}

// ---------- prep kernels ----------
// 8 elems/thread: 2 x float4 in, 1 x u16x8 out
__global__ void cvt_bf16(const float* __restrict__ in, u16* __restrict__ out, int n) {
  int idx = (blockIdx.x * blockDim.x + threadIdx.x) * 8;
  if (idx < n) {
    float4 v0 = *(const float4*)(in + idx);
    float4 v1 = *(const float4*)(in + idx + 4);
    u16x8 o;
    o[0] = f2bf(v0.x); o[1] = f2bf(v0.y); o[2] = f2bf(v0.z); o[3] = f2bf(v0.w);
    o[4] = f2bf(v1.x); o[5] = f2bf(v1.y); o[6] = f2bf(v1.z); o[7] = f2bf(v1.w);
    *(u16x8*)(out + idx) = o;
  }
}

// in [R][Cc] f32 -> out [Cc][R] bf16 ; block (32,8), grid (Cc/32, R/32)
__global__ void transpose_cvt(const float* __restrict__ in, u16* __restrict__ out,
                              int R, int Cc) {
  __shared__ float tile[32][33];
  int c0 = blockIdx.x * 32, r0 = blockIdx.y * 32;
  int tx = threadIdx.x, ty = threadIdx.y;
#pragma unroll
  for (int i = 0; i < 4; ++i)
    tile[ty + i * 8][tx] = in[(size_t)(r0 + ty + i * 8) * Cc + c0 + tx];
  __syncthreads();
#pragma unroll
  for (int i = 0; i < 4; ++i)
    out[(size_t)(c0 + ty + i * 8) * R + r0 + tx] = f2bf(tile[tx][ty + i * 8]);
}

// fused: the three 512x1024 weight transposes in one launch (z = which matrix)
__global__ void transpose_cvt3(const float* __restrict__ W0, const float* __restrict__ W1,
                               const float* __restrict__ W2, u16* __restrict__ out) {
  __shared__ float tile[32][33];
  const int z = blockIdx.z;
  const float* in = (z == 0) ? W0 : (z == 1) ? W1 : W2;
  u16* op = out + (size_t)z * 1024 * 512;
  int c0 = blockIdx.x * 32, r0 = blockIdx.y * 32;
  int tx = threadIdx.x, ty = threadIdx.y;
#pragma unroll
  for (int i = 0; i < 4; ++i)
    tile[ty + i * 8][tx] = in[(size_t)(r0 + ty + i * 8) * 1024 + c0 + tx];
  __syncthreads();
#pragma unroll
  for (int i = 0; i < 4; ++i)
    op[(size_t)(c0 + ty + i * 8) * 512 + r0 + tx] = f2bf(tile[tx][ty + i * 8]);
}

// ---------- QKV projection GEMM (R12 structure; V written in Vt2 layout) ----------
// Q/K outputs in perm layout [bh][c'][d], Q pre-scaled by log2(e)/sqrt(D).
// V (p==2): block y computes the FULL [d][k] plane of Vt2[bh][y] (k=m&127,
// d=j&127); epilogue transposes acc through the 32KB LDS (XOR-swizzled) and
// writes coalesced u16x8 rows.  This replaces the separate vtrans kernel.
__global__ void qkv_gemm(const u16* __restrict__ xb, const u16* __restrict__ wt,
                         const float* __restrict__ bq, const float* __restrict__ bk,
                         const float* __restrict__ bv,
                         u16* __restrict__ qout, u16* __restrict__ kout,
                         u16* __restrict__ vout) {
  __shared__ u16 sAB[16384];   // As 8192 u16 | Bs 8192 u16 ; reused as 128x128 tile
  u16* As = sAB;
  u16* Bs = sAB + 8192;
  const int m0 = blockIdx.x * 128;
  const int n0 = blockIdx.y * 128;
  const int p  = blockIdx.z;
  const u16* wp = wt + (size_t)p * 1024 * 512;
  const float* bias = (p == 0) ? bq : (p == 1) ? bk : bv;
  const float osc = (p == 0) ? 0.12751744116389548f : 1.0f;  // log2(e)/sqrt(128)

  const int tid = threadIdx.x, l = tid & 63, w = tid >> 6;
  const int lr = l & 15, lg = l >> 4;
  const int wr = w >> 1, wc = w & 1;

  f32x4 acc[4][4] = {};

  for (int kt = 0; kt < Fn; kt += 64) {
#pragma unroll
    for (int i = 0; i < 4; ++i) {
      int chb = (i * 4 + w) * 64;
      int ch = chb + l;
      int row = ch >> 3, scc = (ch & 7) ^ (row & 7);
      gload16(xb + (size_t)(m0 + row) * Fn + kt + scc * 8, &As[chb * 8]);
    }
#pragma unroll
    for (int i = 0; i < 4; ++i) {
      int chb = (i * 4 + w) * 64;
      int ch = chb + l;
      int row = ch >> 3, scc = (ch & 7) ^ (row & 7);
      gload16(wp + (size_t)(n0 + row) * Fn + kt + scc * 8, &Bs[chb * 8]);
    }
    __syncthreads();
#pragma unroll
    for (int kk = 0; kk < 2; ++kk) {
      bfrag af[4], bf_[4];
#pragma unroll
      for (int fm = 0; fm < 4; ++fm) {
        int row = wr * 64 + fm * 16 + lr;
        int off = (kk * 4 + lg) ^ (row & 7);
        af[fm] = *(const bfrag*)&As[row * 64 + off * 8];
      }
#pragma unroll
      for (int fn = 0; fn < 4; ++fn) {
        int row = wc * 64 + fn * 16 + lr;
        int off = (kk * 4 + lg) ^ (row & 7);
        bf_[fn] = *(const bfrag*)&Bs[row * 64 + off * 8];
      }
#pragma unroll
      for (int fm = 0; fm < 4; ++fm)
#pragma unroll
        for (int fn = 0; fn < 4; ++fn)
          acc[fm][fn] = mfma16(af[fm], bf_[fn], acc[fm][fn]);
    }
    __syncthreads();
  }

  if (p == 2) {
    // ---- V epilogue: acc -> LDS transpose -> Vt2[bh][y][d][k] coalesced ----
    const int y = n0 >> 7;
#pragma unroll
    for (int fm = 0; fm < 4; ++fm) {
#pragma unroll
      for (int fn = 0; fn < 4; ++fn) {
        int kb = wr * 64 + fm * 16 + lg * 4;       // k base (multiple of 4)
        int d  = wc * 64 + fn * 16 + lr;
        float b0 = bias[n0 + d];
        unsigned p01 = cvtpk(acc[fm][fn][0] + b0, acc[fm][fn][1] + b0);
        unsigned p23 = cvtpk(acc[fm][fn][2] + b0, acc[fm][fn][3] + b0);
        int kx = kb ^ ((d & 7) << 3);              // XOR bits 3-5: pairs stay contiguous
        *(unsigned*)&sAB[d * 128 + kx]     = p01;
        *(unsigned*)&sAB[d * 128 + kx + 2] = p23;
      }
    }
    __syncthreads();
    const int b = m0 >> 10, gh = (m0 & 1023) >> 7;
    u16* outv = vout + ((size_t)((b * 8 + gh) * 8 + y)) * 16384;
#pragma unroll
    for (int i = 0; i < 8; ++i) {
      int g = i * 256 + tid;
      int d = g >> 4, s = g & 15;
      u16x8 vv = *(const u16x8*)&sAB[d * 128 + ((s ^ (d & 7)) << 3)];
      *(u16x8*)&outv[d * 128 + s * 8] = vv;
    }
    return;
  }

  // ---- Q/K epilogue: perm write (h'=c>>7, c'=(c&127)*8+(j>>7), d=j&127) ----
  u16* outp = (p == 0) ? qout : kout;
#pragma unroll
  for (int fm = 0; fm < 4; ++fm) {
#pragma unroll
    for (int r = 0; r < 4; ++r) {
      int m = m0 + wr * 64 + fm * 16 + lg * 4 + r;
      int b = m >> 10, c = m & 1023;
      int gh = c >> 7;
#pragma unroll
      for (int fn = 0; fn < 4; ++fn) {
        int j = n0 + wc * 64 + fn * 16 + lr;
        float v = (acc[fm][fn][r] + bias[j]) * osc;
        int ii = ((c & 127) << 3) | (j >> 7);
        int d = j & 127;
        size_t idx = (((size_t)(b * 8 + gh) * 1024 + ii) << 7) | d;
        outp[idx] = f2bf(v);
      }
    }
  }
}

// ---------- fused flash attention (8-wave block, no-max softmax, Vt2 layout) ----------
// O = softmax(QK^T/sqrt(D))@V - V.  512 blocks (XCD-swizzled) x 512 threads;
// S^T = mfma32(K,Q); P = exp2(S') directly (bounded domain); in-register P^T
// via cvt_pk + permlane32_swap; O^T = mfma32(V^T,P^T); XOR-folded addressing.
// kv order within each 64-tile is PERMUTED consistently on K and V:
// LDS kv-row j = y*8+k'' holds channel c' = t*64 + 8k'' + y, so V chunks come
// straight from Vt2[bh][y][d][t*8..t*8+8) (16B contiguous, gload16-direct).
// Softmax has no max-tracking and lsum is order-independent -> kv order free.
__global__ __launch_bounds__(512, 2)
void attn_kernel(const u16* __restrict__ qp_all, const u16* __restrict__ kp_all,
                 const u16* __restrict__ vt_all, u16* __restrict__ attout) {
  __shared__ u16 smem[2 * 16384];
  char* smb = (char*)smem;

  const int bid = blockIdx.x;
  const int wg = (bid & 7) * 64 + (bid >> 3);
  const int bh = wg >> 2;
  const int qtp = wg & 3;

  const int tid = threadIdx.x, l = tid & 63, w = tid >> 6;   // w in 0..7
  const int q31 = l & 31, hi = l >> 5;

  const u16* qp  = qp_all + (size_t)bh * (Cn * Dn);
  const u16* kp  = kp_all + (size_t)bh * (Cn * Dn);
  const u16* vtp = vt_all + (size_t)bh * (Dn * Cn);   // Vt2[bh]: [y][d][k]
  const int qr0 = qtp * 256 + w * 32;    // wave's 32 q-rows within the head

  const unsigned LK = (unsigned)(q31 * 256) ^ (unsigned)((q31 & 15) * 16) ^ (unsigned)(hi * 16);
  const unsigned LV = 16384u ^ (unsigned)(q31 * 128) ^ (unsigned)((q31 & 7) * 16) ^ (unsigned)(hi * 16);

  const u16* ksrc[2]; const u16* vsrc[2];
  unsigned kdst[2], vdst[2];
#pragma unroll
  for (int c = 0; c < 2; ++c) {
    int ch = c * 512 + tid;
    // K: dest row j holds c' = t*64 + 8*(j&7) + (j>>3); column chunk XOR-preswizzled
    int krow = ch >> 4, kscc = (ch & 15) ^ (krow & 15);
    int csrc = 8 * (krow & 7) + (krow >> 3);
    ksrc[c] = kp + csrc * 128 + kscc * 8;
    // V: dest (row d, slot s) holds y = s^(d&7), 8 consecutive k from Vt2[y][d]
    int vrow = ch >> 3;
    int vy = (ch & 7) ^ (vrow & 7);
    vsrc[c] = vtp + (size_t)vy * 16384 + vrow * 128;
    kdst[c] = (unsigned)((c * 512 + w * 64) * 16);
    vdst[c] = 16384u + (unsigned)((c * 512 + w * 64) * 16);
  }
  auto stage = [&](int t2, unsigned bufb) {
#pragma unroll
    for (int c = 0; c < 2; ++c)
      gload16(ksrc[c] + (size_t)t2 * 8192, smb + (bufb ^ kdst[c]));
#pragma unroll
    for (int c = 0; c < 2; ++c)
      gload16(vsrc[c] + (size_t)t2 * 8, smb + (bufb ^ vdst[c]));
  };

  bfrag aq[8];
#pragma unroll
  for (int kk = 0; kk < 8; ++kk)
    aq[kk] = *(const bfrag*)(qp + (size_t)(qr0 + q31) * Dn + kk * 16 + hi * 8);

  f32x16 ot[4] = {};                 // O^T accumulator: col q=q31, rows d
  float lsum = 0.f;                  // per-lane HALF-sum of exp2 (combined at end)

  stage(0, 0);
  __syncthreads();

  unsigned bufb = 0;
  for (int t = 0; t < 16; ++t) {
    const unsigned nb = bufb ^ 32768u;
    if (t < 15) stage(t + 1, nb);    // lands during this iter's compute
    const unsigned LKb = LK ^ bufb;
    const unsigned LVb = LV ^ bufb;

    f32x16 st0 = {}, st1 = {};
    __builtin_amdgcn_s_setprio(1);
#pragma unroll
    for (int kk = 0; kk < 8; ++kk) {
      bfrag k0 = *(const bfrag*)(smb + (LKb ^ (unsigned)(kk * 32)));
      st0 = mfma32(k0, aq[kk], st0);
      bfrag k1 = *(const bfrag*)(smb + (LKb ^ (unsigned)(8192 + kk * 32)));
      st1 = mfma32(k1, aq[kk], st1);
    }
    __builtin_amdgcn_s_setprio(0);

    float rp[4] = {0.f, 0.f, 0.f, 0.f};
#pragma unroll
    for (int r = 0; r < 16; ++r) {
      float p0 = fexp2(st0[r]);
      st0[r] = p0;
      rp[r & 3] += p0;
    }
#pragma unroll
    for (int r = 0; r < 16; ++r) {
      float p1 = fexp2(st1[r]);
      st1[r] = p1;
      rp[r & 3] += p1;
    }
    lsum += (rp[0] + rp[1]) + (rp[2] + rp[3]);

    bfrag pb[4];
    {
      unsigned c0_[8], c1_[8];
#pragma unroll
      for (int m = 0; m < 8; ++m) {
        c0_[m] = cvtpk(st0[2 * m], st0[2 * m + 1]);
        c1_[m] = cvtpk(st1[2 * m], st1[2 * m + 1]);
      }
#pragma unroll
      for (int kkt = 0; kkt < 2; ++kkt) {
        unsigned a0 = c0_[4 * kkt + 0], b0 = c0_[4 * kkt + 2];
        unsigned a1 = c0_[4 * kkt + 1], b1 = c0_[4 * kkt + 3];
        asm("v_permlane32_swap_b32 %0, %1" : "+v"(a0), "+v"(b0));
        asm("v_permlane32_swap_b32 %0, %1" : "+v"(a1), "+v"(b1));
        u32x4 bw; bw.x = a0; bw.y = a1; bw.z = b0; bw.w = b1;
        pb[kkt] = __builtin_bit_cast(bfrag, bw);
      }
#pragma unroll
      for (int kkt = 0; kkt < 2; ++kkt) {
        unsigned a0 = c1_[4 * kkt + 0], b0 = c1_[4 * kkt + 2];
        unsigned a1 = c1_[4 * kkt + 1], b1 = c1_[4 * kkt + 3];
        asm("v_permlane32_swap_b32 %0, %1" : "+v"(a0), "+v"(b0));
        asm("v_permlane32_swap_b32 %0, %1" : "+v"(a1), "+v"(b1));
        u32x4 bw; bw.x = a0; bw.y = a1; bw.z = b0; bw.w = b1;
        pb[2 + kkt] = __builtin_bit_cast(bfrag, bw);
      }
    }

    __builtin_amdgcn_s_setprio(1);
#pragma unroll
    for (int kk = 0; kk < 4; ++kk) {
#pragma unroll
      for (int dt = 0; dt < 4; ++dt) {
        bfrag vf = *(const bfrag*)(smb + (LVb ^ (unsigned)(dt * 4096 + kk * 32)));
        ot[dt] = mfma32(vf, pb[kk], ot[dt]);
      }
    }
    __builtin_amdgcn_s_setprio(0);
    __syncthreads();  // drains vmcnt(0): prefetch (issued at iter top) landed
    bufb = nb;
  }

  // ---- epilogue: combine half-sums, (O^T/l - V(d,c1)) -> LDS -> write ----
  const float lfull = lsum + __shfl_xor(lsum, 32, 64);
  const float linv = 1.f / lfull;
  const int c1 = qr0 + q31;
  const u16* vcol = vtp + (size_t)(c1 & 7) * 16384 + (c1 >> 3);  // Vt2[y=c1&7][.][k=c1>>3]
  u16* my = smem + w * 4096;
#pragma unroll
  for (int dt = 0; dt < 4; ++dt)
#pragma unroll
    for (int rp2 = 0; rp2 < 8; ++rp2) {
      int reg = 2 * rp2;
      int d = dt * 32 + (reg & 3) + 8 * (reg >> 2) + 4 * hi;
      float v0 = bf2f(vcol[(size_t)d * 128]);
      float v1 = bf2f(vcol[(size_t)(d + 1) * 128]);
      unsigned pk = cvtpk(ot[dt][reg] * linv - v0, ot[dt][reg + 1] * linv - v1);
      *(unsigned*)&my[q31 * 128 + (((d >> 3) ^ (q31 & 7)) << 3) + (d & 7)] = pk;
    }
  const int b = bh >> 3, h = bh & 7;
#pragma unroll
  for (int it = 0; it < 8; ++it) {
    int rowq = it * 4 + (l >> 4);
    int ch = l & 15;
    u16x8 rd = *(const u16x8*)&my[rowq * 128 + ((ch ^ (rowq & 7))) * 8];
    int cg = qr0 + rowq;
    *(u16x8*)&attout[(((size_t)(b * 1024 + cg)) * 8 + h) * 128 + ch * 8] = rd;
  }
}

// ---------- output GEMM: [16384][1024] @ [1024][128] + bias -> f32 ----------
__global__ void out_gemm(const u16* __restrict__ A, const u16* __restrict__ Bt,
                         const float* __restrict__ bias, float* __restrict__ out) {
  __shared__ u16 As[32 * 64];
  __shared__ u16 Bs[128 * 64];
  const int m0 = blockIdx.x * 32;
  const int tid = threadIdx.x, l = tid & 63, w = tid >> 6;
  const int lr = l & 15, lg = l >> 4;
  f32x4 acc[2][2] = {};

  for (int kt = 0; kt < 1024; kt += 64) {
    {   // As: 256 chunks, 1/thread
      int ch = w * 64 + l;
      int row = ch >> 3, scc = (ch & 7) ^ (row & 7);
      gload16(A + (size_t)(m0 + row) * 1024 + kt + scc * 8, &As[(w * 64) * 8]);
    }
#pragma unroll
    for (int i = 0; i < 4; ++i) {   // Bs: 1024 chunks, 4/thread
      int chb = (i * 4 + w) * 64;
      int ch = chb + l;
      int row = ch >> 3, scc = (ch & 7) ^ (row & 7);
      gload16(Bt + (size_t)row * 1024 + kt + scc * 8, &Bs[chb * 8]);
    }
    __syncthreads();
#pragma unroll
    for (int kk = 0; kk < 2; ++kk) {
      bfrag af[2], bf_[2];
#pragma unroll
      for (int fm = 0; fm < 2; ++fm) {
        int row = fm * 16 + lr;
        int off = (kk * 4 + lg) ^ (row & 7);
        af[fm] = *(const bfrag*)&As[row * 64 + off * 8];
      }
#pragma unroll
      for (int fn = 0; fn < 2; ++fn) {
        int row = w * 32 + fn * 16 + lr;
        int off = (kk * 4 + lg) ^ (row & 7);
        bf_[fn] = *(const bfrag*)&Bs[row * 64 + off * 8];
      }
#pragma unroll
      for (int fm = 0; fm < 2; ++fm)
#pragma unroll
        for (int fn = 0; fn < 2; ++fn)
          acc[fm][fn] = mfma16(af[fm], bf_[fn], acc[fm][fn]);
    }
    __syncthreads();
  }
#pragma unroll
  for (int fm = 0; fm < 2; ++fm)
#pragma unroll
    for (int r = 0; r < 4; ++r) {
      int m = m0 + fm * 16 + lg * 4 + r;
#pragma unroll
      for (int fn = 0; fn < 2; ++fn) {
        int j = w * 32 + fn * 16 + lr;
        out[(size_t)m * 128 + j] = acc[fm][fn][r] + bias[j];
      }
    }
}

// ---------- launch ----------
extern "C" void kernel_launch(void* const* d_in, const int* in_sizes, int n_in,
                              void* d_out, int out_size, void* d_ws, size_t ws_size,
                              hipStream_t stream) {
  const float* x   = (const float*)d_in[0];
  const float* Wk  = (const float*)d_in[1];
  const float* bk_ = (const float*)d_in[2];
  const float* Wq  = (const float*)d_in[3];
  const float* bq_ = (const float*)d_in[4];
  const float* Wv  = (const float*)d_in[5];
  const float* bv_ = (const float*)d_in[6];
  const float* Ww0 = (const float*)d_in[7];
  const float* bw0 = (const float*)d_in[8];
  float* out = (float*)d_out;

  char* ws = (char*)d_ws;
  u16* xb   = (u16*)(ws + OFF_XB);
  u16* wt   = (u16*)(ws + OFF_WT);
  u16* w0t  = (u16*)(ws + OFF_W0T);
  u16* qpm  = (u16*)(ws + OFF_Q);
  u16* kpm  = (u16*)(ws + OFF_K);
  u16* vpm  = (u16*)(ws + OFF_V);   // Vt2 layout, written directly by qkv p==2
  u16* attb = (u16*)(ws + OFF_ATT); // attn output

  // prep: cast x (8/thread), transpose+cast weights (3 fused + w0)
  cvt_bf16<<<(M1 * Fn / 8 + 255) / 256, 256, 0, stream>>>(x, xb, M1 * Fn);
  dim3 tb(32, 8);
  transpose_cvt3<<<dim3(32, 16, 3), tb, 0, stream>>>(Wq, Wk, Wv, wt);
  transpose_cvt<<<dim3(4, 32), tb, 0, stream>>>(Ww0, w0t, 1024, 128);

  // projections: Q,K -> perm layout; V -> Vt2 (vtrans eliminated)
  qkv_gemm<<<dim3(128, 8, 3), 256, 0, stream>>>(xb, wt, bq_, bk_, bv_, qpm, kpm, vpm);

  // fused attention (softmax - I folded as O = P@V - V), XCD-swizzled grid
  attn_kernel<<<dim3(512), 512, 0, stream>>>(qpm, kpm, vpm, attb);

  // output projection (f32 out + bias)
  out_gemm<<<512, 256, 0, stream>>>(attb, w0t, bw0, out);
}

// Round 18
// 170.889 us; speedup vs baseline: 1.0692x; 1.0329x over previous
//
#include <hip/hip_runtime.h>
#include <hip/hip_bf16.h>
#include <cstdint>
#include <cstddef>

// ---------- types ----------
using u16 = unsigned short;
typedef __attribute__((ext_vector_type(4))) float f32x4;
typedef __attribute__((ext_vector_type(16))) float f32x16;
typedef __attribute__((ext_vector_type(8))) unsigned short u16x8;
typedef __attribute__((ext_vector_type(4))) unsigned short u16x4;
typedef __attribute__((ext_vector_type(2))) unsigned short u16x2;
typedef __attribute__((ext_vector_type(4))) unsigned int u32x4;
typedef __bf16 bfrag __attribute__((ext_vector_type(8)));   // 8 bf16 = 4 VGPR MFMA operand

constexpr int Hn = 8, Cn = 1024, Dn = 128, Fn = 512, Bn = 16;
constexpr int M1 = Bn * Cn;  // 16384 rows of x / att_out

// workspace layout (bytes)
constexpr size_t OFF_XB  = 0;                                  // x bf16 [16384][512]
constexpr size_t SZ_XB   = (size_t)M1 * Fn * 2;                // 16 MiB
constexpr size_t OFF_WT  = OFF_XB + SZ_XB;                     // Wt bf16 [3][1024][512] (q,k,v)
constexpr size_t SZ_WT   = 3ull * 1024 * 512 * 2;              // 3 MiB
constexpr size_t OFF_W0T = OFF_WT + SZ_WT;                     // Ww0^T bf16 [128][1024]
constexpr size_t SZ_W0T  = 128ull * 1024 * 2;
constexpr size_t OFF_Q   = OFF_W0T + SZ_W0T;                   // q perm [16][8][1024][128] bf16
constexpr size_t SZ_P    = (size_t)Bn * Hn * Cn * Dn * 2;      // 32 MiB each
constexpr size_t OFF_K   = OFF_Q + SZ_P;
constexpr size_t OFF_V   = OFF_K + SZ_P;                       // Vt2: [bh][y][128 d][128 k], c'=8k+y
constexpr size_t OFF_ATT = OFF_V + SZ_P;                       // vals2 bf16 [16384][1024]

// ---------- helpers ----------
__device__ __forceinline__ float bf2f(u16 u) {
  unsigned int x = ((unsigned int)u) << 16;
  return __builtin_bit_cast(float, x);
}
__device__ __forceinline__ u16 f2bf(float f) {
  unsigned int u = __builtin_bit_cast(unsigned int, f);
  u += 0x7fffu + ((u >> 16) & 1u);   // RNE
  return (u16)(u >> 16);
}
__device__ __forceinline__ f32x4 mfma16(bfrag a, bfrag b, f32x4 c) {
  return __builtin_amdgcn_mfma_f32_16x16x32_bf16(a, b, c, 0, 0, 0);
}
__device__ __forceinline__ f32x16 mfma32(bfrag a, bfrag b, f32x16 c) {
  return __builtin_amdgcn_mfma_f32_32x32x16_bf16(a, b, c, 0, 0, 0);
}
// async 16B global->LDS; lds base must be wave-uniform (lane*16 auto-offset)
__device__ __forceinline__ void gload16(const void* g, void* lds) {
  __builtin_amdgcn_global_load_lds(
      (const __attribute__((address_space(1))) unsigned int*)g,
      (__attribute__((address_space(3))) unsigned int*)lds, 16, 0, 0);
}
__device__ __forceinline__ unsigned cvtpk(float lo, float hi) {
  unsigned r;
  asm("v_cvt_pk_bf16_f32 %0, %1, %2" : "=v"(r) : "v"(lo), "v"(hi));
  return r;
}
// raw HW exp2 (1 instr; valid here: |x| < ~2 by construction)
__device__ __forceinline__ float fexp2(float x) {
  float r;
  asm("v_exp_f32 %0, %1" : "=v"(r) : "v"(x));
  return r;
}

// ---------- prep kernels ----------
// 8 elems/thread: 2 x float4 in, 1 x u16x8 out
__global__ void cvt_bf16(const float* __restrict__ in, u16* __restrict__ out, int n) {
  int idx = (blockIdx.x * blockDim.x + threadIdx.x) * 8;
  if (idx < n) {
    float4 v0 = *(const float4*)(in + idx);
    float4 v1 = *(const float4*)(in + idx + 4);
    u16x8 o;
    o[0] = f2bf(v0.x); o[1] = f2bf(v0.y); o[2] = f2bf(v0.z); o[3] = f2bf(v0.w);
    o[4] = f2bf(v1.x); o[5] = f2bf(v1.y); o[6] = f2bf(v1.z); o[7] = f2bf(v1.w);
    *(u16x8*)(out + idx) = o;
  }
}

// in [R][Cc] f32 -> out [Cc][R] bf16 ; block (32,8), grid (Cc/32, R/32)
__global__ void transpose_cvt(const float* __restrict__ in, u16* __restrict__ out,
                              int R, int Cc) {
  __shared__ float tile[32][33];
  int c0 = blockIdx.x * 32, r0 = blockIdx.y * 32;
  int tx = threadIdx.x, ty = threadIdx.y;
#pragma unroll
  for (int i = 0; i < 4; ++i)
    tile[ty + i * 8][tx] = in[(size_t)(r0 + ty + i * 8) * Cc + c0 + tx];
  __syncthreads();
#pragma unroll
  for (int i = 0; i < 4; ++i)
    out[(size_t)(c0 + ty + i * 8) * R + r0 + tx] = f2bf(tile[tx][ty + i * 8]);
}

// fused: the three 512x1024 weight transposes in one launch (z = which matrix)
__global__ void transpose_cvt3(const float* __restrict__ W0, const float* __restrict__ W1,
                               const float* __restrict__ W2, u16* __restrict__ out) {
  __shared__ float tile[32][33];
  const int z = blockIdx.z;
  const float* in = (z == 0) ? W0 : (z == 1) ? W1 : W2;
  u16* op = out + (size_t)z * 1024 * 512;
  int c0 = blockIdx.x * 32, r0 = blockIdx.y * 32;
  int tx = threadIdx.x, ty = threadIdx.y;
#pragma unroll
  for (int i = 0; i < 4; ++i)
    tile[ty + i * 8][tx] = in[(size_t)(r0 + ty + i * 8) * 1024 + c0 + tx];
  __syncthreads();
#pragma unroll
  for (int i = 0; i < 4; ++i)
    op[(size_t)(c0 + ty + i * 8) * 512 + r0 + tx] = f2bf(tile[tx][ty + i * 8]);
}

// ---------- QKV projection GEMM (R12 structure; V written in Vt2 layout) ----------
// Q/K outputs in perm layout [bh][c'][d], Q pre-scaled by log2(e)/sqrt(D).
// V (p==2): block y computes the FULL [d][k] plane of Vt2[bh][y] (k=m&127,
// d=j&127); epilogue transposes acc through the 32KB LDS (XOR-swizzled) and
// writes coalesced u16x8 rows.  This replaces the separate vtrans kernel.
__global__ void qkv_gemm(const u16* __restrict__ xb, const u16* __restrict__ wt,
                         const float* __restrict__ bq, const float* __restrict__ bk,
                         const float* __restrict__ bv,
                         u16* __restrict__ qout, u16* __restrict__ kout,
                         u16* __restrict__ vout) {
  __shared__ u16 sAB[16384];   // As 8192 u16 | Bs 8192 u16 ; reused as 128x128 tile
  u16* As = sAB;
  u16* Bs = sAB + 8192;
  const int m0 = blockIdx.x * 128;
  const int n0 = blockIdx.y * 128;
  const int p  = blockIdx.z;
  const u16* wp = wt + (size_t)p * 1024 * 512;
  const float* bias = (p == 0) ? bq : (p == 1) ? bk : bv;
  const float osc = (p == 0) ? 0.12751744116389548f : 1.0f;  // log2(e)/sqrt(128)

  const int tid = threadIdx.x, l = tid & 63, w = tid >> 6;
  const int lr = l & 15, lg = l >> 4;
  const int wr = w >> 1, wc = w & 1;

  f32x4 acc[4][4] = {};

  for (int kt = 0; kt < Fn; kt += 64) {
#pragma unroll
    for (int i = 0; i < 4; ++i) {
      int chb = (i * 4 + w) * 64;
      int ch = chb + l;
      int row = ch >> 3, scc = (ch & 7) ^ (row & 7);
      gload16(xb + (size_t)(m0 + row) * Fn + kt + scc * 8, &As[chb * 8]);
    }
#pragma unroll
    for (int i = 0; i < 4; ++i) {
      int chb = (i * 4 + w) * 64;
      int ch = chb + l;
      int row = ch >> 3, scc = (ch & 7) ^ (row & 7);
      gload16(wp + (size_t)(n0 + row) * Fn + kt + scc * 8, &Bs[chb * 8]);
    }
    __syncthreads();
#pragma unroll
    for (int kk = 0; kk < 2; ++kk) {
      bfrag af[4], bf_[4];
#pragma unroll
      for (int fm = 0; fm < 4; ++fm) {
        int row = wr * 64 + fm * 16 + lr;
        int off = (kk * 4 + lg) ^ (row & 7);
        af[fm] = *(const bfrag*)&As[row * 64 + off * 8];
      }
#pragma unroll
      for (int fn = 0; fn < 4; ++fn) {
        int row = wc * 64 + fn * 16 + lr;
        int off = (kk * 4 + lg) ^ (row & 7);
        bf_[fn] = *(const bfrag*)&Bs[row * 64 + off * 8];
      }
#pragma unroll
      for (int fm = 0; fm < 4; ++fm)
#pragma unroll
        for (int fn = 0; fn < 4; ++fn)
          acc[fm][fn] = mfma16(af[fm], bf_[fn], acc[fm][fn]);
    }
    __syncthreads();
  }

  if (p == 2) {
    // ---- V epilogue: acc -> LDS transpose -> Vt2[bh][y][d][k] coalesced ----
    const int y = n0 >> 7;
#pragma unroll
    for (int fm = 0; fm < 4; ++fm) {
#pragma unroll
      for (int fn = 0; fn < 4; ++fn) {
        int kb = wr * 64 + fm * 16 + lg * 4;       // k base (multiple of 4)
        int d  = wc * 64 + fn * 16 + lr;
        float b0 = bias[n0 + d];
        unsigned p01 = cvtpk(acc[fm][fn][0] + b0, acc[fm][fn][1] + b0);
        unsigned p23 = cvtpk(acc[fm][fn][2] + b0, acc[fm][fn][3] + b0);
        int kx = kb ^ ((d & 7) << 3);              // XOR bits 3-5: pairs stay contiguous
        *(unsigned*)&sAB[d * 128 + kx]     = p01;
        *(unsigned*)&sAB[d * 128 + kx + 2] = p23;
      }
    }
    __syncthreads();
    const int b = m0 >> 10, gh = (m0 & 1023) >> 7;
    u16* outv = vout + ((size_t)((b * 8 + gh) * 8 + y)) * 16384;
#pragma unroll
    for (int i = 0; i < 8; ++i) {
      int g = i * 256 + tid;
      int d = g >> 4, s = g & 15;
      u16x8 vv = *(const u16x8*)&sAB[d * 128 + ((s ^ (d & 7)) << 3)];
      *(u16x8*)&outv[d * 128 + s * 8] = vv;
    }
    return;
  }

  // ---- Q/K epilogue: perm write (h'=c>>7, c'=(c&127)*8+(j>>7), d=j&127) ----
  u16* outp = (p == 0) ? qout : kout;
#pragma unroll
  for (int fm = 0; fm < 4; ++fm) {
#pragma unroll
    for (int r = 0; r < 4; ++r) {
      int m = m0 + wr * 64 + fm * 16 + lg * 4 + r;
      int b = m >> 10, c = m & 1023;
      int gh = c >> 7;
#pragma unroll
      for (int fn = 0; fn < 4; ++fn) {
        int j = n0 + wc * 64 + fn * 16 + lr;
        float v = (acc[fm][fn][r] + bias[j]) * osc;
        int ii = ((c & 127) << 3) | (j >> 7);
        int d = j & 127;
        size_t idx = (((size_t)(b * 8 + gh) * 1024 + ii) << 7) | d;
        outp[idx] = f2bf(v);
      }
    }
  }
}

// ---------- fused flash attention (8-wave block, no-max softmax, y-major kv tiles) ----------
// O = softmax(QK^T/sqrt(D))@V - V.  512 blocks (XCD-swizzled) x 512 threads;
// S^T = mfma32(K,Q); P = exp2(S') directly (bounded domain); in-register P^T
// via cvt_pk + permlane32_swap; O^T = mfma32(V^T,P^T); XOR-folded addressing.
// kv tiles iterate (y, kb): tile t = y*2+kb covers channels c' = 8k+y,
// k in [64kb, 64kb+64).  K stage: row j holds c' = 512kb+8j+y (whole 256B
// perm-rows, row-granular scatter only).  V stage: 8 lanes (same d) cover a
// CONTIGUOUS 128B run of Vt2[y][d][64kb..64kb+64] -- R16-grade coalescing,
// fixing R17's 16B cross-plane gather (attn 79->95us regression).
// kv order is a global permutation: no-max softmax + order-independent lsum
// make it semantics-free.  P/V slot consistency: V slot s entry e = channel
// 512kb + 64s + 8e + y = K row j=8s+e's channel.
__global__ __launch_bounds__(512, 2)
void attn_kernel(const u16* __restrict__ qp_all, const u16* __restrict__ kp_all,
                 const u16* __restrict__ vt_all, u16* __restrict__ attout) {
  __shared__ u16 smem[2 * 16384];
  char* smb = (char*)smem;

  const int bid = blockIdx.x;
  const int wg = (bid & 7) * 64 + (bid >> 3);
  const int bh = wg >> 2;
  const int qtp = wg & 3;

  const int tid = threadIdx.x, l = tid & 63, w = tid >> 6;   // w in 0..7
  const int q31 = l & 31, hi = l >> 5;

  const u16* qp  = qp_all + (size_t)bh * (Cn * Dn);
  const u16* kp  = kp_all + (size_t)bh * (Cn * Dn);
  const u16* vtp = vt_all + (size_t)bh * (Dn * Cn);   // Vt2[bh]: [y][d][k]
  const int qr0 = qtp * 256 + w * 32;    // wave's 32 q-rows within the head

  const unsigned LK = (unsigned)(q31 * 256) ^ (unsigned)((q31 & 15) * 16) ^ (unsigned)(hi * 16);
  const unsigned LV = 16384u ^ (unsigned)(q31 * 128) ^ (unsigned)((q31 & 7) * 16) ^ (unsigned)(hi * 16);

  const u16* ksrc[2]; const u16* vsrc[2];
  unsigned kdst[2], vdst[2];
#pragma unroll
  for (int c = 0; c < 2; ++c) {
    int ch = c * 512 + tid;
    // K: dest row j holds channel c' = 512*kb + 8*j + y (channel-row stride 8)
    int krow = ch >> 4, kscc = (ch & 15) ^ (krow & 15);
    ksrc[c] = kp + (size_t)krow * 1024 + kscc * 8;
    // V: dest (row d, phys slot) -> logical slot s; source Vt2[y][d][64kb+8s]
    int vrow = ch >> 3;
    int vslog = (ch & 7) ^ (vrow & 7);
    vsrc[c] = vtp + (size_t)vrow * 128 + vslog * 8;
    kdst[c] = (unsigned)((c * 512 + w * 64) * 16);
    vdst[c] = 16384u + (unsigned)((c * 512 + w * 64) * 16);
  }
  auto stage = [&](int t2, unsigned bufb) {
    const int y = t2 >> 1, kb = t2 & 1;
    const size_t koff = (size_t)kb * 65536 + (size_t)y * 128;   // elems
    const size_t voff = (size_t)y * 16384 + (size_t)kb * 64;    // elems
#pragma unroll
    for (int c = 0; c < 2; ++c)
      gload16(ksrc[c] + koff, smb + (bufb ^ kdst[c]));
#pragma unroll
    for (int c = 0; c < 2; ++c)
      gload16(vsrc[c] + voff, smb + (bufb ^ vdst[c]));
  };

  bfrag aq[8];
#pragma unroll
  for (int kk = 0; kk < 8; ++kk)
    aq[kk] = *(const bfrag*)(qp + (size_t)(qr0 + q31) * Dn + kk * 16 + hi * 8);

  f32x16 ot[4] = {};                 // O^T accumulator: col q=q31, rows d
  float lsum = 0.f;                  // per-lane HALF-sum of exp2 (combined at end)

  stage(0, 0);
  __syncthreads();

  unsigned bufb = 0;
  for (int t = 0; t < 16; ++t) {
    const unsigned nb = bufb ^ 32768u;
    if (t < 15) stage(t + 1, nb);    // lands during this iter's compute
    const unsigned LKb = LK ^ bufb;
    const unsigned LVb = LV ^ bufb;

    f32x16 st0 = {}, st1 = {};
    __builtin_amdgcn_s_setprio(1);
#pragma unroll
    for (int kk = 0; kk < 8; ++kk) {
      bfrag k0 = *(const bfrag*)(smb + (LKb ^ (unsigned)(kk * 32)));
      st0 = mfma32(k0, aq[kk], st0);
      bfrag k1 = *(const bfrag*)(smb + (LKb ^ (unsigned)(8192 + kk * 32)));
      st1 = mfma32(k1, aq[kk], st1);
    }
    __builtin_amdgcn_s_setprio(0);

    float rp[4] = {0.f, 0.f, 0.f, 0.f};
#pragma unroll
    for (int r = 0; r < 16; ++r) {
      float p0 = fexp2(st0[r]);
      st0[r] = p0;
      rp[r & 3] += p0;
    }
#pragma unroll
    for (int r = 0; r < 16; ++r) {
      float p1 = fexp2(st1[r]);
      st1[r] = p1;
      rp[r & 3] += p1;
    }
    lsum += (rp[0] + rp[1]) + (rp[2] + rp[3]);

    bfrag pb[4];
    {
      unsigned c0_[8], c1_[8];
#pragma unroll
      for (int m = 0; m < 8; ++m) {
        c0_[m] = cvtpk(st0[2 * m], st0[2 * m + 1]);
        c1_[m] = cvtpk(st1[2 * m], st1[2 * m + 1]);
      }
#pragma unroll
      for (int kkt = 0; kkt < 2; ++kkt) {
        unsigned a0 = c0_[4 * kkt + 0], b0 = c0_[4 * kkt + 2];
        unsigned a1 = c0_[4 * kkt + 1], b1 = c0_[4 * kkt + 3];
        asm("v_permlane32_swap_b32 %0, %1" : "+v"(a0), "+v"(b0));
        asm("v_permlane32_swap_b32 %0, %1" : "+v"(a1), "+v"(b1));
        u32x4 bw; bw.x = a0; bw.y = a1; bw.z = b0; bw.w = b1;
        pb[kkt] = __builtin_bit_cast(bfrag, bw);
      }
#pragma unroll
      for (int kkt = 0; kkt < 2; ++kkt) {
        unsigned a0 = c1_[4 * kkt + 0], b0 = c1_[4 * kkt + 2];
        unsigned a1 = c1_[4 * kkt + 1], b1 = c1_[4 * kkt + 3];
        asm("v_permlane32_swap_b32 %0, %1" : "+v"(a0), "+v"(b0));
        asm("v_permlane32_swap_b32 %0, %1" : "+v"(a1), "+v"(b1));
        u32x4 bw; bw.x = a0; bw.y = a1; bw.z = b0; bw.w = b1;
        pb[2 + kkt] = __builtin_bit_cast(bfrag, bw);
      }
    }

    __builtin_amdgcn_s_setprio(1);
#pragma unroll
    for (int kk = 0; kk < 4; ++kk) {
#pragma unroll
      for (int dt = 0; dt < 4; ++dt) {
        bfrag vf = *(const bfrag*)(smb + (LVb ^ (unsigned)(dt * 4096 + kk * 32)));
        ot[dt] = mfma32(vf, pb[kk], ot[dt]);
      }
    }
    __builtin_amdgcn_s_setprio(0);
    __syncthreads();  // drains vmcnt(0): prefetch (issued at iter top) landed
    bufb = nb;
  }

  // ---- epilogue: combine half-sums, (O^T/l - V(d,c1)) -> LDS -> write ----
  const float lfull = lsum + __shfl_xor(lsum, 32, 64);
  const float linv = 1.f / lfull;
  const int c1 = qr0 + q31;
  const u16* vcol = vtp + (size_t)(c1 & 7) * 16384 + (c1 >> 3);  // Vt2[y=c1&7][.][k=c1>>3]
  u16* my = smem + w * 4096;
#pragma unroll
  for (int dt = 0; dt < 4; ++dt)
#pragma unroll
    for (int rp2 = 0; rp2 < 8; ++rp2) {
      int reg = 2 * rp2;
      int d = dt * 32 + (reg & 3) + 8 * (reg >> 2) + 4 * hi;
      float v0 = bf2f(vcol[(size_t)d * 128]);
      float v1 = bf2f(vcol[(size_t)(d + 1) * 128]);
      unsigned pk = cvtpk(ot[dt][reg] * linv - v0, ot[dt][reg + 1] * linv - v1);
      *(unsigned*)&my[q31 * 128 + (((d >> 3) ^ (q31 & 7)) << 3) + (d & 7)] = pk;
    }
  const int b = bh >> 3, h = bh & 7;
#pragma unroll
  for (int it = 0; it < 8; ++it) {
    int rowq = it * 4 + (l >> 4);
    int ch = l & 15;
    u16x8 rd = *(const u16x8*)&my[rowq * 128 + ((ch ^ (rowq & 7))) * 8];
    int cg = qr0 + rowq;
    *(u16x8*)&attout[(((size_t)(b * 1024 + cg)) * 8 + h) * 128 + ch * 8] = rd;
  }
}

// ---------- output GEMM: [16384][1024] @ [1024][128] + bias -> f32 ----------
__global__ void out_gemm(const u16* __restrict__ A, const u16* __restrict__ Bt,
                         const float* __restrict__ bias, float* __restrict__ out) {
  __shared__ u16 As[32 * 64];
  __shared__ u16 Bs[128 * 64];
  const int m0 = blockIdx.x * 32;
  const int tid = threadIdx.x, l = tid & 63, w = tid >> 6;
  const int lr = l & 15, lg = l >> 4;
  f32x4 acc[2][2] = {};

  for (int kt = 0; kt < 1024; kt += 64) {
    {   // As: 256 chunks, 1/thread
      int ch = w * 64 + l;
      int row = ch >> 3, scc = (ch & 7) ^ (row & 7);
      gload16(A + (size_t)(m0 + row) * 1024 + kt + scc * 8, &As[(w * 64) * 8]);
    }
#pragma unroll
    for (int i = 0; i < 4; ++i) {   // Bs: 1024 chunks, 4/thread
      int chb = (i * 4 + w) * 64;
      int ch = chb + l;
      int row = ch >> 3, scc = (ch & 7) ^ (row & 7);
      gload16(Bt + (size_t)row * 1024 + kt + scc * 8, &Bs[chb * 8]);
    }
    __syncthreads();
#pragma unroll
    for (int kk = 0; kk < 2; ++kk) {
      bfrag af[2], bf_[2];
#pragma unroll
      for (int fm = 0; fm < 2; ++fm) {
        int row = fm * 16 + lr;
        int off = (kk * 4 + lg) ^ (row & 7);
        af[fm] = *(const bfrag*)&As[row * 64 + off * 8];
      }
#pragma unroll
      for (int fn = 0; fn < 2; ++fn) {
        int row = w * 32 + fn * 16 + lr;
        int off = (kk * 4 + lg) ^ (row & 7);
        bf_[fn] = *(const bfrag*)&Bs[row * 64 + off * 8];
      }
#pragma unroll
      for (int fm = 0; fm < 2; ++fm)
#pragma unroll
        for (int fn = 0; fn < 2; ++fn)
          acc[fm][fn] = mfma16(af[fm], bf_[fn], acc[fm][fn]);
    }
    __syncthreads();
  }
#pragma unroll
  for (int fm = 0; fm < 2; ++fm)
#pragma unroll
    for (int r = 0; r < 4; ++r) {
      int m = m0 + fm * 16 + lg * 4 + r;
#pragma unroll
      for (int fn = 0; fn < 2; ++fn) {
        int j = w * 32 + fn * 16 + lr;
        out[(size_t)m * 128 + j] = acc[fm][fn][r] + bias[j];
      }
    }
}

// ---------- launch ----------
extern "C" void kernel_launch(void* const* d_in, const int* in_sizes, int n_in,
                              void* d_out, int out_size, void* d_ws, size_t ws_size,
                              hipStream_t stream) {
  const float* x   = (const float*)d_in[0];
  const float* Wk  = (const float*)d_in[1];
  const float* bk_ = (const float*)d_in[2];
  const float* Wq  = (const float*)d_in[3];
  const float* bq_ = (const float*)d_in[4];
  const float* Wv  = (const float*)d_in[5];
  const float* bv_ = (const float*)d_in[6];
  const float* Ww0 = (const float*)d_in[7];
  const float* bw0 = (const float*)d_in[8];
  float* out = (float*)d_out;

  char* ws = (char*)d_ws;
  u16* xb   = (u16*)(ws + OFF_XB);
  u16* wt   = (u16*)(ws + OFF_WT);
  u16* w0t  = (u16*)(ws + OFF_W0T);
  u16* qpm  = (u16*)(ws + OFF_Q);
  u16* kpm  = (u16*)(ws + OFF_K);
  u16* vpm  = (u16*)(ws + OFF_V);   // Vt2 layout, written directly by qkv p==2
  u16* attb = (u16*)(ws + OFF_ATT); // attn output

  // prep: cast x (8/thread), transpose+cast weights (3 fused + w0)
  cvt_bf16<<<(M1 * Fn / 8 + 255) / 256, 256, 0, stream>>>(x, xb, M1 * Fn);
  dim3 tb(32, 8);
  transpose_cvt3<<<dim3(32, 16, 3), tb, 0, stream>>>(Wq, Wk, Wv, wt);
  transpose_cvt<<<dim3(4, 32), tb, 0, stream>>>(Ww0, w0t, 1024, 128);

  // projections: Q,K -> perm layout; V -> Vt2 (vtrans eliminated)
  qkv_gemm<<<dim3(128, 8, 3), 256, 0, stream>>>(xb, wt, bq_, bk_, bv_, qpm, kpm, vpm);

  // fused attention (softmax - I folded as O = P@V - V), y-major kv tiles
  attn_kernel<<<dim3(512), 512, 0, stream>>>(qpm, kpm, vpm, attb);

  // output projection (f32 out + bias)
  out_gemm<<<512, 256, 0, stream>>>(attb, w0t, bw0, out);
}